// Round 7
// baseline (487.997 us; speedup 1.0000x reference)
//
#include <hip/hip_runtime.h>
#include <stdint.h>

// MinkFormerBlock on MI355X (gfx950). I/O: f32 in, f32 out (verified R8).
// R20: channel-phase split -> L2-resident gather. Evidence chain: per-CU-tap
// time ~4600cyc across ALL schedules (R15 ring / R18 depth-1 / R19 2-block
// TLP within 25%), MFMA needs only ~620cyc -> memory service saturated.
// FETCH_SIZE 337MB vs 36MB working set = L2-miss re-fetch x10: the 8MB
// gather table misses the 4MB/XCD L2 (random nbr, no locality); 164 miss-
// lines/CU-tap x ~600cyc L3 latency / ~28 outstanding = the ~4000cyc wall.
// Fix: split K (channels) into 2 phases of 64ch; phase ph gathers only bytes
// [ph*128,+128) of each row -> 4MB line-footprint fits XCD L2 -> gather
// becomes L2-hit. acc persists in regs across phases. Linearized: subtap
// tau in [0,2N), tap=tau%N, ph=tau>=N; R19's proven per-tap schedule/ledger
// applies uniformly over tau (B-half 4 DMA, A 2, idx 1 per subtap; waits
// GG_W(4)/GG_WB(3) steady, (2),(0) tail; own-B certified BEFORE barrier;
// prefetch never drains). Zero-conflict 128B-stride LDS layout (R15/R18
// measured 0). LDS 32KB/block, 2 blocks/CU. idx re-read per phase (+16MB
// streamed).
//
//   cvt:       xb = bf16(x)            (aliases h_b, dead until ew1)
//   wt:        WT* = bf16(W^T)  [tap][Cout][Cin]
//   gg<1,0>:   a = xb @ Wa1 ; v = xb @ Wv1     (bf16)
//   gg<125,1>: g = gather(a,nbr5)@W5 * v       (bf16, fused gate)
//   gg<27,2>:  t = gather(g,nbr3a)@W31         (f32)
//   bn+fin -> sc1,sh1 ; ew1: res=bf16->g_b, h=bf16(relu)->h_b
//   gg<27,2>:  t2 = gather(h,nbr3b)@W32        (f32)
//   bn+fin -> sc2,sh2 ; ew2: d_out = relu(t2*sc+sh + res)  (f32)

#define NPTS 32768
#define C 128
#define EPS 1e-5f

typedef unsigned short u16;
using bfrag = __attribute__((ext_vector_type(8))) short;   // 8 bf16 = 4 VGPRs
using f32x4 = __attribute__((ext_vector_type(4))) float;

__device__ __forceinline__ float b2f(u16 u) {
  union { unsigned int i; float f; } x;
  x.i = ((unsigned int)u) << 16;
  return x.f;
}
__device__ __forceinline__ u16 f2b(float f) {
  union { float f; unsigned int i; } x;
  x.f = f;
  unsigned int r = x.i + 0x7FFFu + ((x.i >> 16) & 1u);   // RNE
  return (u16)(r >> 16);
}

// async global->LDS, 16 B per lane; LDS dest is wave-uniform base + lane*16.
__device__ __forceinline__ void g2l16(const void* g, void* l) {
  __builtin_amdgcn_global_load_lds(
      (const __attribute__((address_space(1))) unsigned int*)g,
      (__attribute__((address_space(3))) unsigned int*)l,
      16, 0, 0);
}

// counted vmcnt wait + scheduling fence
#define GG_W(N)                                                            \
  asm volatile("s_waitcnt vmcnt(" #N ")" ::: "memory");                    \
  __builtin_amdgcn_sched_barrier(0)

// counted vmcnt + lgkm drain, then block barrier (own-B certified BEFORE
// the barrier -> union certified after; lgkm drains ds_reads for WAR)
#define GG_WB(N)                                                           \
  asm volatile("s_waitcnt vmcnt(" #N ") lgkmcnt(0)" ::: "memory");         \
  __builtin_amdgcn_s_barrier();                                            \
  __builtin_amdgcn_sched_barrier(0)

// =====================================================================
// Gather-GEMM, channel-phase split. Block = 64x128 output, 4 waves row-
// split: wave wv owns rows [wv*16,+16); acc 8 mfma_f32_16x16x32_bf16 frags.
// Subtap tau in [0, 2*NTAPS): tap = tau%NTAPS, ph = tau/NTAPS. Per subtap:
// A: 2 plain dwordx4/wave: lane (lsub,lm) reads 16B of row id's phase piece
//    (src + id*256 + ph*128) at byte kk2*64+lsub*16.
// B: LDS 32KB = 2 x 16KB buffers [128 col][128B]; stage 4 x 1KB DMA/wave;
//    lane (r8,cs8): global WT+tap*32K+col*256+ph*128+((cs8^(col&7))<<4) ->
//    slot cs8 (slot s holds chunk s^(col&7)). Read (kk2,lsub): chunk
//    (kk2*4+lsub)^(col&7) -- measured-zero-conflict (R15/R18).
// EPI: 0 bf16 out; 1 bf16(acc*vmul); 2 f32 out.
// =====================================================================
template <int NTAPS, int EPI>
__global__ __launch_bounds__(256, 1)
void gg_kernel(const u16* __restrict__ src, const u16* __restrict__ WT,
               const int* __restrict__ nbr, u16* __restrict__ outb,
               float* __restrict__ outf, const u16* __restrict__ vmul) {
  __shared__ uint4 lds[2048];          // 32 KB: two 16 KB B buffers
  char* const b0 = (char*)lds;
  char* const b1 = (char*)lds + 16384;

  const int tid  = threadIdx.x;
  const int lane = tid & 63;
  const int wv   = tid >> 6;
  const int lsub = lane >> 4, lm = lane & 15;
  const int r8   = lane >> 3;          // DMA: col within instr (0..7)
  const int cs8  = lane & 7;           // DMA: chunk slot (0..7, 16 B)
  const int row0 = blockIdx.x * 64;

  f32x4 acc[8];
#pragma unroll
  for (int j = 0; j < 8; j++) acc[j] = (f32x4)(0.0f);

  auto tOf  = [](int tau) { return tau < NTAPS ? tau : tau - NTAPS; };
  auto phOf = [](int tau) { return tau < NTAPS ? 0 : 1; };

  // ---- B half-stage for subtap tau into 16KB buffer nb (4 DMA/wave)
  auto stageB = [&](char* nb, int tau) {
    const char* wt = (const char*)WT + ((size_t)tOf(tau) << 15)
                   + (phOf(tau) << 7);
#pragma unroll
    for (int j = 0; j < 4; j++) {
      const int col0 = wv * 32 + j * 8;
      const int col  = col0 + r8;
      g2l16(wt + ((size_t)col << 8) + ((cs8 ^ (col & 7)) << 4),
            nb + col0 * 128);
    }
  };

  // ---- idx load (plain: waitcnt pass protects all copies/spills)
  auto loadIdx = [&](int& d, int tau) {
    const int gr = row0 + wv * 16 + lm;
    d = nbr[(size_t)gr * NTAPS + tOf(tau)];
  };

  // ---- A gather: 2 plain dwordx4 of the row's phase piece (per-wave)
  auto loadA = [&](bfrag (&af)[2], int id, int tau) {
    const char* rb = (const char*)src + ((size_t)(unsigned)id << 8)
                   + (phOf(tau) << 7) + lsub * 16;
    af[0] = *(const bfrag*)(rb);
    af[1] = *(const bfrag*)(rb + 64);
  };

  // ---- one subtap of MFMA: A from regs, B-half from LDS buffer buf
  auto computeP = [&](const bfrag (&af)[2], const char* buf) {
#pragma unroll
    for (int kk2 = 0; kk2 < 2; kk2++) {
      bfrag bg[8];
#pragma unroll
      for (int ct = 0; ct < 8; ct++) {
        const int col = ct * 16 + lm;
        bg[ct] = *(const bfrag*)(buf + col * 128
                                 + (((kk2 * 4 + lsub) ^ (col & 7)) << 4));
      }
#pragma unroll
      for (int ct = 0; ct < 8; ct++)
        acc[ct] = __builtin_amdgcn_mfma_f32_16x16x32_bf16(
            af[kk2], bg[ct], acc[ct], 0, 0, 0);
    }
  };

  bfrag af0[2], af1[2];

  if constexpr (NTAPS == 1) {
    // dense 1x1: identity rows, both halves staged, full drain, compute
    const char* rb = (const char*)src
                   + (size_t)(row0 + wv * 16 + lm) * 256 + lsub * 16;
    af0[0] = *(const bfrag*)(rb);
    af0[1] = *(const bfrag*)(rb + 64);
    af1[0] = *(const bfrag*)(rb + 128);
    af1[1] = *(const bfrag*)(rb + 192);
    stageB(b0, 0);                   // tap0 ph0
    stageB(b1, 1);                   // tap0 ph1  (tau=1 -> tOf=0, phOf=1)
    GG_WB(0);
    computeP(af0, b0);
    computeP(af1, b1);
  } else {
    constexpr int S = 2 * NTAPS;     // subtaps (even)
    int idE, idO;                    // even-subtap / odd-subtap index
    // ---- prologue: B(0) first, then A(0), I(1)  -> [B0 4, A0 2, I1 1]
    loadIdx(idE, 0);                 // +1
    GG_W(0);                         // retire I(0)
    stageB(b0, 0);                   // +4
    loadA(af0, idE, 0);              // +2
    loadIdx(idO, 1);                 // +1
    GG_WB(3);                        // retire B(0); leave [A0 2, I1 1]=3

#pragma unroll 1
    for (int t = 0; t < S - 2; t += 2) {
      // ---- even subtap t: compute af0 from b0
      stageB(b1, t + 1);             // -> [A(t)2, I(t+1)1, B(t+1)4]=7
      GG_W(4);                       // retire A(t)+I(t+1)
      loadA(af1, idO, t + 1);        // A(t+1)
      loadIdx(idE, t + 2);
      __builtin_amdgcn_sched_barrier(0);
      computeP(af0, b0);
      GG_WB(3);                      // retire B(t+1); leave [A(t+1)2, I1]
      // ---- odd subtap t+1: compute af1 from b1
      stageB(b0, t + 2);
      GG_W(4);                       // retire A(t+1)+I(t+2)
      loadA(af0, idE, t + 2);        // A(t+2)
      loadIdx(idO, t + 3);
      __builtin_amdgcn_sched_barrier(0);
      computeP(af1, b1);
      GG_WB(3);                      // retire B(t+2)
    }
    // ---- tail subtap S-2 (even): last B stage, last A load
    stageB(b1, S - 1);               // -> [A(S-2)2, I(S-1)1, B(S-1)4]=7
    GG_W(4);                         // retire A(S-2)+I(S-1)
    loadA(af1, idO, S - 1);          // A(S-1)
    __builtin_amdgcn_sched_barrier(0);
    computeP(af0, b0);
    GG_WB(2);                        // retire B(S-1); leave [A(S-1)2]
    // ---- tail subtap S-1 (odd)
    GG_W(0);                         // retire A(S-1)
    computeP(af1, b1);
  }

  // ---- epilogue write. C/D: col = lane&15, row = lsub*4 + reg.
  {
    const int rowb = row0 + wv * 16 + lsub * 4;
#pragma unroll
    for (int ct = 0; ct < 8; ct++) {
      const int c = ct * 16 + lm;
#pragma unroll
      for (int reg = 0; reg < 4; reg++) {
        const size_t off = (size_t)(rowb + reg) * C + c;
        const float v = acc[ct][reg];
        if (EPI == 0)      outb[off] = f2b(v);
        else if (EPI == 1) outb[off] = f2b(v * b2f(vmul[off]));
        else               outf[off] = v;
      }
    }
  }
}

// ---- f32 -> bf16 bulk convert (for x) ------------------------------------
__global__ __launch_bounds__(256)
void cvt_kernel(const float* __restrict__ x, u16* __restrict__ xb) {
  const int i = (blockIdx.x * 256 + threadIdx.x) * 4;
  const float4 v = *(const float4*)(x + i);
  ushort4 o;
  o.x = f2b(v.x); o.y = f2b(v.y); o.z = f2b(v.z); o.w = f2b(v.w);
  *(ushort4*)(xb + i) = o;
}

// ---- weights: f32 [..,Cin,Cout] -> bf16 [..,Cout,Cin] --------------------
__global__ __launch_bounds__(256)
void wt_kernel(const float* __restrict__ W5, const float* __restrict__ W31,
               const float* __restrict__ W32, const float* __restrict__ Wa1,
               const float* __restrict__ Wv1,
               u16* __restrict__ T5, u16* __restrict__ T31, u16* __restrict__ T32,
               u16* __restrict__ Ta1, u16* __restrict__ Tv1) {
  const int b = blockIdx.x;
  const float* w;
  u16* o;
  if (b < 125)       { w = W5  + (size_t)b * 16384;         o = T5  + (size_t)b * 16384; }
  else if (b < 152)  { w = W31 + (size_t)(b - 125) * 16384; o = T31 + (size_t)(b - 125) * 16384; }
  else if (b < 179)  { w = W32 + (size_t)(b - 152) * 16384; o = T32 + (size_t)(b - 152) * 16384; }
  else if (b == 179) { w = Wa1; o = Ta1; }
  else               { w = Wv1; o = Tv1; }
  __shared__ u16 tile[128 * 129];
  for (int i = threadIdx.x; i < C * C; i += 256)
    tile[(i & 127) * 129 + (i >> 7)] = f2b(w[i]);
  __syncthreads();
  for (int i = threadIdx.x; i < C * C; i += 256)
    o[i] = tile[(i >> 7) * 129 + (i & 127)];
}

// ---- BN partials (f32): block b owns rows [b*128, +128) ------------------
__global__ __launch_bounds__(256)
void bnp_kernel(const float* __restrict__ t, float* __restrict__ psum,
                float* __restrict__ psq) {
  const int b = blockIdx.x;
  const int c = threadIdx.x & 127;
  const int h = threadIdx.x >> 7;
  const float* p = t + (size_t)(b * 128 + h * 64) * C + c;
  float s = 0.f, q = 0.f;
#pragma unroll 8
  for (int j = 0; j < 64; j++) {
    const float v = p[(size_t)j * C];
    s += v; q += v * v;
  }
  __shared__ float ls[256], lq[256];
  ls[threadIdx.x] = s; lq[threadIdx.x] = q;
  __syncthreads();
  if (h == 0) {
    psum[b * 128 + c] = ls[c] + ls[c + 128];
    psq[b * 128 + c]  = lq[c] + lq[c + 128];
  }
}

// ---- bnfin: block c reduces 256 partials (parallel) ----------------------
__global__ __launch_bounds__(256)
void bnfin_kernel(const float* __restrict__ psum, const float* __restrict__ psq,
                  const float* __restrict__ gamma, const float* __restrict__ beta,
                  float* __restrict__ scale, float* __restrict__ shift) {
  const int c = blockIdx.x;
  const int t = threadIdx.x;
  float s = psum[(size_t)t * 128 + c];
  float q = psq[(size_t)t * 128 + c];
#pragma unroll
  for (int o = 32; o > 0; o >>= 1) {
    s += __shfl_down(s, o);
    q += __shfl_down(q, o);
  }
  __shared__ float ls[4], lq[4];
  if ((t & 63) == 0) { ls[t >> 6] = s; lq[t >> 6] = q; }
  __syncthreads();
  if (t == 0) {
    s = ls[0] + ls[1] + ls[2] + ls[3];
    q = lq[0] + lq[1] + lq[2] + lq[3];
    const float mean = s * (1.0f / NPTS);
    const float var  = q * (1.0f / NPTS) - mean * mean;
    const float sc   = rsqrtf(var + EPS) * gamma[c];
    scale[c] = sc;
    shift[c] = beta[c] - mean * sc;
  }
}

// ---- ew1: o = t*sc+sh + x; res=bf16(o); h=bf16(relu o) -------------------
__global__ __launch_bounds__(256)
void ew1_kernel(const float* __restrict__ t, const float* __restrict__ x,
                const float* __restrict__ scale, const float* __restrict__ shift,
                u16* __restrict__ res, u16* __restrict__ h) {
  const int i = blockIdx.x * 256 + threadIdx.x;
  const int c = i & 127;
  const float o = t[i] * scale[c] + shift[c] + x[i];
  res[i] = f2b(o);
  h[i] = f2b(o < 0.f ? 0.f : o);
}

// ---- ew2: y = relu(t2*sc+sh + res) -> f32 d_out --------------------------
__global__ __launch_bounds__(256)
void ew2_kernel(const float* __restrict__ t2, const u16* __restrict__ res,
                const float* __restrict__ scale, const float* __restrict__ shift,
                float* __restrict__ y) {
  const int i = blockIdx.x * 256 + threadIdx.x;
  const int c = i & 127;
  const float o = t2[i] * scale[c] + shift[c] + b2f(res[i]);
  y[i] = o < 0.f ? 0.f : o;
}

// =====================================================================
extern "C" void kernel_launch(void* const* d_in, const int* in_sizes, int n_in,
                              void* d_out, int out_size, void* d_ws, size_t ws_size,
                              hipStream_t stream) {
  (void)in_sizes; (void)n_in; (void)out_size; (void)ws_size;

  const float* x   = (const float*)d_in[0];
  const float* Wa1 = (const float*)d_in[1];
  const float* Wv1 = (const float*)d_in[2];
  const float* W5  = (const float*)d_in[3];
  const float* W31 = (const float*)d_in[4];
  const float* W32 = (const float*)d_in[5];
  const float* g1  = (const float*)d_in[6];
  const float* b1  = (const float*)d_in[7];
  const float* g2  = (const float*)d_in[8];
  const float* b2  = (const float*)d_in[9];
  const int* nbr5  = (const int*)d_in[10];
  const int* nbr3a = (const int*)d_in[11];
  const int* nbr3b = (const int*)d_in[12];

  // ---- workspace (~39.8 MB) ----
  char* w = (char*)d_ws;
  u16* WT5  = (u16*)w; w += 4096000;
  u16* WT31 = (u16*)w; w += 884736;
  u16* WT32 = (u16*)w; w += 884736;
  u16* WTa1 = (u16*)w; w += 32768;
  u16* WTv1 = (u16*)w; w += 32768;
  char* AV  = w;       w += 16777216;          // a | v ; later t/t2 (f32)
  u16*   a_b = (u16*)AV;
  u16*   v_b = (u16*)(AV + 8388608);
  float* tf  = (float*)AV;
  u16* g_b  = (u16*)w; w += 8388608;           // g ; later res (bf16)
  u16* h_b  = (u16*)w; w += 8388608;           // xb first, then h (bf16)
  u16* xb   = h_b;                             // alias: xb dead before ew1
  float* psum = (float*)w; w += 131072;
  float* psq  = (float*)w; w += 131072;
  float* sc1  = (float*)w; w += 512;
  float* sh1  = (float*)w; w += 512;
  float* sc2  = (float*)w; w += 512;
  float* sh2  = (float*)w; w += 512;

  const dim3 B256(256), GG(NPTS / 64), GBN(256), GEW(NPTS * C / 256);
  float* yout = (float*)d_out;

  cvt_kernel<<<dim3(NPTS * C / 1024), B256, 0, stream>>>(x, xb);
  wt_kernel<<<dim3(181), B256, 0, stream>>>(W5, W31, W32, Wa1, Wv1,
                                            WT5, WT31, WT32, WTa1, WTv1);

  // a = xb @ Wa1 ; v = xb @ Wv1
  gg_kernel<1, 0><<<GG, B256, 0, stream>>>(xb, WTa1, nullptr, a_b, nullptr, nullptr);
  gg_kernel<1, 0><<<GG, B256, 0, stream>>>(xb, WTv1, nullptr, v_b, nullptr, nullptr);

  // g = gather125(a)@W5 * v
  gg_kernel<125, 1><<<GG, B256, 0, stream>>>(a_b, WT5, nbr5, g_b, nullptr, v_b);

  // t = gather27(g)@W31 -> f32 over AV (a,v dead)
  gg_kernel<27, 2><<<GG, B256, 0, stream>>>(g_b, WT31, nbr3a, nullptr, tf, nullptr);
  bnp_kernel<<<GBN, B256, 0, stream>>>(tf, psum, psq);
  bnfin_kernel<<<dim3(128), B256, 0, stream>>>(psum, psq, g1, b1, sc1, sh1);
  ew1_kernel<<<GEW, B256, 0, stream>>>(tf, x, sc1, sh1, g_b, h_b);   // res->g_b, h->h_b (xb dead)

  // t2 = gather27(h)@W32 -> f32 over AV (t dead)
  gg_kernel<27, 2><<<GG, B256, 0, stream>>>(h_b, WT32, nbr3b, nullptr, tf, nullptr);
  bnp_kernel<<<GBN, B256, 0, stream>>>(tf, psum, psq);
  bnfin_kernel<<<dim3(128), B256, 0, stream>>>(psum, psq, g2, b2, sc2, sh2);
  ew2_kernel<<<GEW, B256, 0, stream>>>(tf, g_b, sc2, sh2, yout);
}

// Round 8
// 409.125 us; speedup vs baseline: 1.1928x; 1.1928x over previous
//
#include <hip/hip_runtime.h>
#include <stdint.h>

// MinkFormerBlock on MI355X (gfx950). I/O: f32 in, f32 out (verified R8).
// R21: all-LDS deep pipeline (R15 structure) + 8-wave blocks + channel-phase.
// R20's decisive result: FETCH halved (gather L2-resident) but time flat ->
// not HBM-bound, not residency-bound. Invariant across R17-R20: per-wave
// outstanding depth ~5-7 ops, because compute consumed COMPILER-VISIBLE
// register loads (A/idx) -> compiler inserts conservative drains before the
// MFMA block, collapsing the counted-vmcnt pipeline. R15 (190us, fastest)
// was the only design with NO register-load consumers in the loop (all data
// global->LDS DMA, idx via asm) -> its depth (~20 ops/wave) was real.
// R21 = R15 structure with: 8 waves/block (512 thr, 128 rows: B staged once
// per CU-tap, -33% requests) + R20's channel-phase stage order (stage =
// (tap,half): all h0 then all h1 -> gather stays L2-resident, FETCH ~177MB).
// Stage s: tap = s<N?s:s-N, h = s<N?0:1. 4-deep LDS ring (4 x 32KB = 128KB:
// A-half 16KB + B-half 16KB). Per stage per wave: A 2 DMA + B 2 DMA + idx 2
// asm loads = 6-op group; ONE wait per stage: vmcnt(12)+lgkm(0)+barrier
// (retires stage s's group = 3rd-newest; 12-18 ops stay in flight). idx for
// stage k loaded at k-6, consumed at k-3, retired by that stage's wait.
// Ledger FIFO-traced: prologue (3x6 groups), steady 12, tail 12,10,8,8,4,0.
// Zero-conflict 128B-stride LDS layout (R15/R18 measured 0).
//
//   cvt:       xb = bf16(x)            (aliases h_b, dead until ew1)
//   wt:        WT* = bf16(W^T)  [tap][Cout][Cin]
//   gg<1,0>:   a = xb @ Wa1 ; v = xb @ Wv1     (bf16)
//   gg<125,1>: g = gather(a,nbr5)@W5 * v       (bf16, fused gate)
//   gg<27,2>:  t = gather(g,nbr3a)@W31         (f32)
//   bn+fin -> sc1,sh1 ; ew1: res=bf16->g_b, h=bf16(relu)->h_b
//   gg<27,2>:  t2 = gather(h,nbr3b)@W32        (f32)
//   bn+fin -> sc2,sh2 ; ew2: d_out = relu(t2*sc+sh + res)  (f32)

#define NPTS 32768
#define C 128
#define EPS 1e-5f

typedef unsigned short u16;
using bfrag = __attribute__((ext_vector_type(8))) short;   // 8 bf16 = 4 VGPRs
using f32x4 = __attribute__((ext_vector_type(4))) float;

__device__ __forceinline__ float b2f(u16 u) {
  union { unsigned int i; float f; } x;
  x.i = ((unsigned int)u) << 16;
  return x.f;
}
__device__ __forceinline__ u16 f2b(float f) {
  union { float f; unsigned int i; } x;
  x.f = f;
  unsigned int r = x.i + 0x7FFFu + ((x.i >> 16) & 1u);   // RNE
  return (u16)(r >> 16);
}

// async global->LDS, 16 B per lane; LDS dest is wave-uniform base + lane*16.
__device__ __forceinline__ void g2l16(const void* g, void* l) {
  __builtin_amdgcn_global_load_lds(
      (const __attribute__((address_space(1))) unsigned int*)g,
      (__attribute__((address_space(3))) unsigned int*)l,
      16, 0, 0);
}

#define GG_W(N)                                                            \
  asm volatile("s_waitcnt vmcnt(" #N ")" ::: "memory");                    \
  __builtin_amdgcn_sched_barrier(0)

// counted vmcnt (own stage-group certified BEFORE barrier) + lgkm drain
// (prev stage's ds_reads, WAR safety) + block barrier + sched fence.
#define GG_WB(N)                                                           \
  asm volatile("s_waitcnt vmcnt(" #N ") lgkmcnt(0)" ::: "memory");         \
  __builtin_amdgcn_s_barrier();                                            \
  __builtin_amdgcn_sched_barrier(0)

// =====================================================================
// Gather-GEMM. Block = 128x128 output, 512 threads, 8 waves row-split:
// wave wv owns rows [wv*16,+16); acc 8 f32x4 frags (16 rows x 128 cols).
// Stage s in [0, 2*NTAPS): tap = s<N?s:s-N, half = s<N?0:1 (channel-phase).
// LDS ring: buf[s&3] = A-half [128 rows][128B] + B-half [128 cols][128B].
// Stage group (issued at stage s-3, for stage s): per wave
//   A: 2 g2l16 (8 rows x 128B each; lane (r8,cs8): row wv*16+j*8+r8,
//      global chunk cs8^r8 of src+id*256+h*128 -> LDS slot cs8)
//   B: 2 g2l16 (cols wv*16+j*8+r8 of WT+tap*32K+h*128, same swizzle)
//   idx: 2 asm global_load_dword (lane holds idx of ITS staging row),
//      loaded for stage s+6, consumed at s+3, retired by stage s+3's wait.
// Compute: 2 k-steps; af/bg ds_read_b128 at slot (kk2*4+lsub)^(row&7) --
// measured-zero-conflict layout. 16 MFMA/stage/wave.
// EPI: 0 bf16 out; 1 bf16(acc*vmul); 2 f32 out.
// =====================================================================
template <int NTAPS, int EPI>
__global__ __launch_bounds__(512, 1)
void gg_kernel(const u16* __restrict__ src, const u16* __restrict__ WT,
               const int* __restrict__ nbr, u16* __restrict__ outb,
               float* __restrict__ outf, const u16* __restrict__ vmul) {
  __shared__ uint4 lds[8192];          // 128 KB: four 32 KB stage buffers
  char* const base = (char*)lds;
  char* const bufs[4] = {base, base + 32768, base + 65536, base + 98304};

  const int tid  = threadIdx.x;
  const int lane = tid & 63;
  const int wv   = tid >> 6;           // 0..7
  const int lsub = lane >> 4, lm = lane & 15;
  const int r8   = lane >> 3;          // DMA: row/col within instr (0..7)
  const int cs8  = lane & 7;           // DMA: chunk slot (0..7, 16 B)
  const int row0 = blockIdx.x * 128;

  f32x4 acc[8];
#pragma unroll
  for (int j = 0; j < 8; j++) acc[j] = (f32x4)(0.0f);

  // ---- idx loads (asm: invisible to waitcnt pass; retired by the manual
  // waits exactly 3 stages before use; ~80 VGPR total -> no allocator risk)
  auto loadIdx = [&](int (&d)[2], int st) {
    const int tp = st < NTAPS ? st : st - NTAPS;
#pragma unroll
    for (int j = 0; j < 2; j++) {
      const int gr = row0 + wv * 16 + j * 8 + r8;
      const int* p = nbr + (size_t)gr * NTAPS + tp;
      asm volatile("global_load_dword %0, %1, off"
                   : "=v"(d[j]) : "v"(p) : "memory");
    }
  };

  // ---- A half-stage for stage st (2 DMA/wave)
  auto stageA = [&](char* buf, const int (&id)[2], int st) {
    const int h = st < NTAPS ? 0 : 1;
#pragma unroll
    for (int j = 0; j < 2; j++) {
      const char* gp = (const char*)src + ((size_t)(unsigned)id[j] << 8)
                     + (h << 7) + ((cs8 ^ r8) << 4);
      g2l16(gp, buf + (wv * 16 + j * 8) * 128);
    }
  };

  // ---- B half-stage for stage st (2 DMA/wave)
  auto stageB = [&](char* buf, int st) {
    const int tp = st < NTAPS ? st : st - NTAPS;
    const int h = st < NTAPS ? 0 : 1;
    const char* wt = (const char*)WT + ((size_t)tp << 15) + (h << 7);
#pragma unroll
    for (int j = 0; j < 2; j++) {
      const int col = wv * 16 + j * 8 + r8;
      g2l16(wt + ((size_t)col << 8) + ((cs8 ^ r8) << 4),
            buf + 16384 + (wv * 16 + j * 8) * 128);
    }
  };

  // ---- one stage of MFMA: A and B both from LDS (no vmem-reg consumers)
  auto computeS = [&](const char* buf) {
#pragma unroll
    for (int kk2 = 0; kk2 < 2; kk2++) {
      const int arow = wv * 16 + lm;
      const bfrag af = *(const bfrag*)(buf + arow * 128
                           + (((kk2 * 4 + lsub) ^ (lm & 7)) << 4));
      bfrag bg[8];
#pragma unroll
      for (int ct = 0; ct < 8; ct++) {
        const int col = ct * 16 + lm;
        bg[ct] = *(const bfrag*)(buf + 16384 + col * 128
                                 + (((kk2 * 4 + lsub) ^ (col & 7)) << 4));
      }
#pragma unroll
      for (int ct = 0; ct < 8; ct++)
        acc[ct] = __builtin_amdgcn_mfma_f32_16x16x32_bf16(
            af, bg[ct], acc[ct], 0, 0, 0);
    }
  };

  // ---- dense variant: A from registers (NTAPS==1 only; single drain)
  auto computeD = [&](const bfrag (&af)[2], const char* buf) {
#pragma unroll
    for (int kk2 = 0; kk2 < 2; kk2++) {
      bfrag bg[8];
#pragma unroll
      for (int ct = 0; ct < 8; ct++) {
        const int col = ct * 16 + lm;
        bg[ct] = *(const bfrag*)(buf + 16384 + col * 128
                                 + (((kk2 * 4 + lsub) ^ (col & 7)) << 4));
      }
#pragma unroll
      for (int ct = 0; ct < 8; ct++)
        acc[ct] = __builtin_amdgcn_mfma_f32_16x16x32_bf16(
            af[kk2], bg[ct], acc[ct], 0, 0, 0);
    }
  };

  if constexpr (NTAPS == 1) {
    // dense 1x1: own rows, plain A loads, B halves into bufs 0/1, one drain
    bfrag a0[2], a1[2];
    const char* rb = (const char*)src
                   + (size_t)(row0 + wv * 16 + lm) * 256 + lsub * 16;
    a0[0] = *(const bfrag*)(rb);
    a0[1] = *(const bfrag*)(rb + 64);
    a1[0] = *(const bfrag*)(rb + 128);
    a1[1] = *(const bfrag*)(rb + 192);
    stageB(bufs[0], 0);                  // tap0 h0
    stageB(bufs[1], 1);                  // tap0 h1
    GG_WB(0);
    computeD(a0, bufs[0]);
    computeD(a1, bufs[1]);
  } else {
    constexpr int S = 2 * NTAPS;         // stages; N odd -> S-6 % 4 == 0
    int idr[4][2], ip0[2], ip1[2], ip2[2];
    // ---- prologue: idx(0..2) -> drain -> groups G(-3),G(-2),G(-1)
    loadIdx(ip0, 0); loadIdx(ip1, 1); loadIdx(ip2, 2);   // 6 ops
    GG_W(0);
    stageA(bufs[0], ip0, 0); stageB(bufs[0], 0); loadIdx(idr[1], 3);
    stageA(bufs[1], ip1, 1); stageB(bufs[1], 1); loadIdx(idr[2], 4);
    stageA(bufs[2], ip2, 2); stageB(bufs[2], 2); loadIdx(idr[3], 5);
    // FIFO = 18 = three 6-op groups; steady invariant holds from stage 0.

    // ---- main: stage s consumes idr[(s+1)&3] (idx of stage s+3, loaded at
    // s-3), loads idr[s&3] <- idx(stage s+6). One wait per stage.
#define GG_SUB(p)                                                          \
    GG_WB(12);                                                             \
    stageA(bufs[((p) + 3) & 3], idr[((p) + 1) & 3], s + (p) + 3);          \
    stageB(bufs[((p) + 3) & 3], s + (p) + 3);                              \
    loadIdx(idr[(p) & 3], s + (p) + 6);                                    \
    computeS(bufs[(p) & 3]);

#pragma unroll 1
    for (int s = 0; s < S - 6; s += 4) {
      GG_SUB(0)
      GG_SUB(1)
      GG_SUB(2)
      GG_SUB(3)
    }
#undef GG_SUB

    // ---- tail: stages S-6..S-1 (phases 0,1,2,3,0,1), no idx loads.
    // idx slots: S%4==2 -> idx(S-3)@slot1, idx(S-2)@slot2, idx(S-1)@slot3.
    GG_WB(12);
    stageA(bufs[3], idr[1], S - 3); stageB(bufs[3], S - 3);
    computeS(bufs[0]);                   // stage S-6
    GG_WB(10);
    stageA(bufs[0], idr[2], S - 2); stageB(bufs[0], S - 2);
    computeS(bufs[1]);                   // stage S-5
    GG_WB(8);
    stageA(bufs[1], idr[3], S - 1); stageB(bufs[1], S - 1);
    computeS(bufs[2]);                   // stage S-4
    GG_WB(8);
    computeS(bufs[3]);                   // stage S-3
    GG_WB(4);
    computeS(bufs[0]);                   // stage S-2
    GG_WB(0);
    computeS(bufs[1]);                   // stage S-1
  }

  // ---- epilogue write. C/D: col = lane&15, row = lsub*4 + reg.
  {
    const int rowb = row0 + wv * 16 + lsub * 4;
#pragma unroll
    for (int ct = 0; ct < 8; ct++) {
      const int c = ct * 16 + lm;
#pragma unroll
      for (int reg = 0; reg < 4; reg++) {
        const size_t off = (size_t)(rowb + reg) * C + c;
        const float v = acc[ct][reg];
        if (EPI == 0)      outb[off] = f2b(v);
        else if (EPI == 1) outb[off] = f2b(v * b2f(vmul[off]));
        else               outf[off] = v;
      }
    }
  }
}

// ---- f32 -> bf16 bulk convert (for x) ------------------------------------
__global__ __launch_bounds__(256)
void cvt_kernel(const float* __restrict__ x, u16* __restrict__ xb) {
  const int i = (blockIdx.x * 256 + threadIdx.x) * 4;
  const float4 v = *(const float4*)(x + i);
  ushort4 o;
  o.x = f2b(v.x); o.y = f2b(v.y); o.z = f2b(v.z); o.w = f2b(v.w);
  *(ushort4*)(xb + i) = o;
}

// ---- weights: f32 [..,Cin,Cout] -> bf16 [..,Cout,Cin] --------------------
__global__ __launch_bounds__(256)
void wt_kernel(const float* __restrict__ W5, const float* __restrict__ W31,
               const float* __restrict__ W32, const float* __restrict__ Wa1,
               const float* __restrict__ Wv1,
               u16* __restrict__ T5, u16* __restrict__ T31, u16* __restrict__ T32,
               u16* __restrict__ Ta1, u16* __restrict__ Tv1) {
  const int b = blockIdx.x;
  const float* w;
  u16* o;
  if (b < 125)       { w = W5  + (size_t)b * 16384;         o = T5  + (size_t)b * 16384; }
  else if (b < 152)  { w = W31 + (size_t)(b - 125) * 16384; o = T31 + (size_t)(b - 125) * 16384; }
  else if (b < 179)  { w = W32 + (size_t)(b - 152) * 16384; o = T32 + (size_t)(b - 152) * 16384; }
  else if (b == 179) { w = Wa1; o = Ta1; }
  else               { w = Wv1; o = Tv1; }
  __shared__ u16 tile[128 * 129];
  for (int i = threadIdx.x; i < C * C; i += 256)
    tile[(i & 127) * 129 + (i >> 7)] = f2b(w[i]);
  __syncthreads();
  for (int i = threadIdx.x; i < C * C; i += 256)
    o[i] = tile[(i >> 7) * 129 + (i & 127)];
}

// ---- BN partials (f32): block b owns rows [b*128, +128) ------------------
__global__ __launch_bounds__(256)
void bnp_kernel(const float* __restrict__ t, float* __restrict__ psum,
                float* __restrict__ psq) {
  const int b = blockIdx.x;
  const int c = threadIdx.x & 127;
  const int h = threadIdx.x >> 7;
  const float* p = t + (size_t)(b * 128 + h * 64) * C + c;
  float s = 0.f, q = 0.f;
#pragma unroll 8
  for (int j = 0; j < 64; j++) {
    const float v = p[(size_t)j * C];
    s += v; q += v * v;
  }
  __shared__ float ls[256], lq[256];
  ls[threadIdx.x] = s; lq[threadIdx.x] = q;
  __syncthreads();
  if (h == 0) {
    psum[b * 128 + c] = ls[c] + ls[c + 128];
    psq[b * 128 + c]  = lq[c] + lq[c + 128];
  }
}

// ---- bnfin: block c reduces 256 partials (parallel) ----------------------
__global__ __launch_bounds__(256)
void bnfin_kernel(const float* __restrict__ psum, const float* __restrict__ psq,
                  const float* __restrict__ gamma, const float* __restrict__ beta,
                  float* __restrict__ scale, float* __restrict__ shift) {
  const int c = blockIdx.x;
  const int t = threadIdx.x;
  float s = psum[(size_t)t * 128 + c];
  float q = psq[(size_t)t * 128 + c];
#pragma unroll
  for (int o = 32; o > 0; o >>= 1) {
    s += __shfl_down(s, o);
    q += __shfl_down(q, o);
  }
  __shared__ float ls[4], lq[4];
  if ((t & 63) == 0) { ls[t >> 6] = s; lq[t >> 6] = q; }
  __syncthreads();
  if (t == 0) {
    s = ls[0] + ls[1] + ls[2] + ls[3];
    q = lq[0] + lq[1] + lq[2] + lq[3];
    const float mean = s * (1.0f / NPTS);
    const float var  = q * (1.0f / NPTS) - mean * mean;
    const float sc   = rsqrtf(var + EPS) * gamma[c];
    scale[c] = sc;
    shift[c] = beta[c] - mean * sc;
  }
}

// ---- ew1: o = t*sc+sh + x; res=bf16(o); h=bf16(relu o) -------------------
__global__ __launch_bounds__(256)
void ew1_kernel(const float* __restrict__ t, const float* __restrict__ x,
                const float* __restrict__ scale, const float* __restrict__ shift,
                u16* __restrict__ res, u16* __restrict__ h) {
  const int i = blockIdx.x * 256 + threadIdx.x;
  const int c = i & 127;
  const float o = t[i] * scale[c] + shift[c] + x[i];
  res[i] = f2b(o);
  h[i] = f2b(o < 0.f ? 0.f : o);
}

// ---- ew2: y = relu(t2*sc+sh + res) -> f32 d_out --------------------------
__global__ __launch_bounds__(256)
void ew2_kernel(const float* __restrict__ t2, const u16* __restrict__ res,
                const float* __restrict__ scale, const float* __restrict__ shift,
                float* __restrict__ y) {
  const int i = blockIdx.x * 256 + threadIdx.x;
  const int c = i & 127;
  const float o = t2[i] * scale[c] + shift[c] + b2f(res[i]);
  y[i] = o < 0.f ? 0.f : o;
}

// =====================================================================
extern "C" void kernel_launch(void* const* d_in, const int* in_sizes, int n_in,
                              void* d_out, int out_size, void* d_ws, size_t ws_size,
                              hipStream_t stream) {
  (void)in_sizes; (void)n_in; (void)out_size; (void)ws_size;

  const float* x   = (const float*)d_in[0];
  const float* Wa1 = (const float*)d_in[1];
  const float* Wv1 = (const float*)d_in[2];
  const float* W5  = (const float*)d_in[3];
  const float* W31 = (const float*)d_in[4];
  const float* W32 = (const float*)d_in[5];
  const float* g1  = (const float*)d_in[6];
  const float* b1  = (const float*)d_in[7];
  const float* g2  = (const float*)d_in[8];
  const float* b2  = (const float*)d_in[9];
  const int* nbr5  = (const int*)d_in[10];
  const int* nbr3a = (const int*)d_in[11];
  const int* nbr3b = (const int*)d_in[12];

  // ---- workspace (~39.8 MB) ----
  char* w = (char*)d_ws;
  u16* WT5  = (u16*)w; w += 4096000;
  u16* WT31 = (u16*)w; w += 884736;
  u16* WT32 = (u16*)w; w += 884736;
  u16* WTa1 = (u16*)w; w += 32768;
  u16* WTv1 = (u16*)w; w += 32768;
  char* AV  = w;       w += 16777216;          // a | v ; later t/t2 (f32)
  u16*   a_b = (u16*)AV;
  u16*   v_b = (u16*)(AV + 8388608);
  float* tf  = (float*)AV;
  u16* g_b  = (u16*)w; w += 8388608;           // g ; later res (bf16)
  u16* h_b  = (u16*)w; w += 8388608;           // xb first, then h (bf16)
  u16* xb   = h_b;                             // alias: xb dead before ew1
  float* psum = (float*)w; w += 131072;
  float* psq  = (float*)w; w += 131072;
  float* sc1  = (float*)w; w += 512;
  float* sh1  = (float*)w; w += 512;
  float* sc2  = (float*)w; w += 512;
  float* sh2  = (float*)w; w += 512;

  const dim3 B512(512), GG(NPTS / 128), B256(256), GBN(256), GEW(NPTS * C / 256);
  float* yout = (float*)d_out;

  cvt_kernel<<<dim3(NPTS * C / 1024), B256, 0, stream>>>(x, xb);
  wt_kernel<<<dim3(181), B256, 0, stream>>>(W5, W31, W32, Wa1, Wv1,
                                            WT5, WT31, WT32, WTa1, WTv1);

  // a = xb @ Wa1 ; v = xb @ Wv1
  gg_kernel<1, 0><<<GG, B512, 0, stream>>>(xb, WTa1, nullptr, a_b, nullptr, nullptr);
  gg_kernel<1, 0><<<GG, B512, 0, stream>>>(xb, WTv1, nullptr, v_b, nullptr, nullptr);

  // g = gather125(a)@W5 * v
  gg_kernel<125, 1><<<GG, B512, 0, stream>>>(a_b, WT5, nbr5, g_b, nullptr, v_b);

  // t = gather27(g)@W31 -> f32 over AV (a,v dead)
  gg_kernel<27, 2><<<GG, B512, 0, stream>>>(g_b, WT31, nbr3a, nullptr, tf, nullptr);
  bnp_kernel<<<GBN, B256, 0, stream>>>(tf, psum, psq);
  bnfin_kernel<<<dim3(128), B256, 0, stream>>>(psum, psq, g1, b1, sc1, sh1);
  ew1_kernel<<<GEW, B256, 0, stream>>>(tf, x, sc1, sh1, g_b, h_b);   // res->g_b, h->h_b (xb dead)

  // t2 = gather27(h)@W32 -> f32 over AV (t dead)
  gg_kernel<27, 2><<<GG, B512, 0, stream>>>(h_b, WT32, nbr3b, nullptr, tf, nullptr);
  bnp_kernel<<<GBN, B256, 0, stream>>>(tf, psum, psq);
  bnfin_kernel<<<dim3(128), B256, 0, stream>>>(psum, psq, g2, b2, sc2, sh2);
  ew2_kernel<<<GEW, B256, 0, stream>>>(tf, g_b, sc2, sh2, yout);
}

// Round 9
// 376.887 us; speedup vs baseline: 1.2948x; 1.0855x over previous
//
#include <hip/hip_runtime.h>
#include <stdint.h>

// MinkFormerBlock on MI355X (gfx950). I/O: f32 in, f32 out (verified R8).
// R22: R21 + 4x2 wave tiling (LDS-read bandwidth fix). R21's counters
// triangulated the wall: FETCH 168MB / HBM 11% (traffic irrelevant), depth
// verified, yet stage ~1950cyc. Accounting: 8 waves x 18 ds_read_b128/stage
// (16-row strip tile reads 1 A + 8 B frags per kk-step) = 144 b128/CU-stage
// x ~12cyc (m134 throughput) = 1728cyc ~= the whole stage. B is read 8x
// redundantly. Fix: waves as 4x2 grid, wave tile 32 rows x 64 cols -> 2 A +
// 4 B = 6 b128/kk-step, 96 b128/CU-stage -> ~1400cyc/stage predicted.
// Staging/ledger/idx/swizzle/barriers BYTE-IDENTICAL to R21 (compute and
// epilogue indexing only; barrier decouples staging map from compute map).
// R21 recap: all-LDS deep pipeline (no register-load consumers in loop ->
// counted vmcnt depth is real), 8-wave 128x128 blocks, channel-phase stage
// order (stage=(tap,half), gather L2-resident), 4-deep 32KB ring, 6-op
// groups, one vmcnt(12)+lgkm+barrier per stage, asm idx loads retired 3
// stages before use. Ledger FIFO-traced: steady 12; tail 12,10,8,8,4,0.
//
//   cvt:       xb = bf16(x)            (aliases h_b, dead until ew1)
//   wt:        WT* = bf16(W^T)  [tap][Cout][Cin]
//   gg<1,0>:   a = xb @ Wa1 ; v = xb @ Wv1     (bf16)
//   gg<125,1>: g = gather(a,nbr5)@W5 * v       (bf16, fused gate)
//   gg<27,2>:  t = gather(g,nbr3a)@W31         (f32)
//   bn+fin -> sc1,sh1 ; ew1: res=bf16->g_b, h=bf16(relu)->h_b
//   gg<27,2>:  t2 = gather(h,nbr3b)@W32        (f32)
//   bn+fin -> sc2,sh2 ; ew2: d_out = relu(t2*sc+sh + res)  (f32)

#define NPTS 32768
#define C 128
#define EPS 1e-5f

typedef unsigned short u16;
using bfrag = __attribute__((ext_vector_type(8))) short;   // 8 bf16 = 4 VGPRs
using f32x4 = __attribute__((ext_vector_type(4))) float;

__device__ __forceinline__ float b2f(u16 u) {
  union { unsigned int i; float f; } x;
  x.i = ((unsigned int)u) << 16;
  return x.f;
}
__device__ __forceinline__ u16 f2b(float f) {
  union { float f; unsigned int i; } x;
  x.f = f;
  unsigned int r = x.i + 0x7FFFu + ((x.i >> 16) & 1u);   // RNE
  return (u16)(r >> 16);
}

// async global->LDS, 16 B per lane; LDS dest is wave-uniform base + lane*16.
__device__ __forceinline__ void g2l16(const void* g, void* l) {
  __builtin_amdgcn_global_load_lds(
      (const __attribute__((address_space(1))) unsigned int*)g,
      (__attribute__((address_space(3))) unsigned int*)l,
      16, 0, 0);
}

#define GG_W(N)                                                            \
  asm volatile("s_waitcnt vmcnt(" #N ")" ::: "memory");                    \
  __builtin_amdgcn_sched_barrier(0)

// counted vmcnt (own stage-group certified BEFORE barrier) + lgkm drain
// (prev stage's ds_reads, WAR safety) + block barrier + sched fence.
#define GG_WB(N)                                                           \
  asm volatile("s_waitcnt vmcnt(" #N ") lgkmcnt(0)" ::: "memory");         \
  __builtin_amdgcn_s_barrier();                                            \
  __builtin_amdgcn_sched_barrier(0)

// =====================================================================
// Gather-GEMM. Block = 128x128 output, 512 threads, 8 waves as 4x2 grid:
// wave (wr=wv>>1, wc=wv&1) owns rows [wr*32,+32) x cols [wc*64,+64);
// acc[2][4] f32x4 frags; 16 MFMA/stage/wave; 6 ds_read_b128/kk-step.
// Stage s in [0, 2*NTAPS): tap = s<N?s:s-N, half = s<N?0:1 (channel-phase).
// LDS ring: buf[s&3] = A-half [128 rows][128B] + B-half [128 cols][128B].
// Stage group (issued at stage s-3, for stage s): per wave (by wv, NOT
// wr/wc -- barrier decouples): A 2 g2l16 (rows wv*16+j*8+r8, chunk cs8^r8
// of src+id*256+h*128), B 2 g2l16 (cols likewise of WT+tap*32K+h*128),
// idx 2 asm global_load_dword (for stage s+6, consumed s+3).
// Reads at slot (kk2*4+lsub)^(row&7): measured-zero-conflict layout.
// EPI: 0 bf16 out; 1 bf16(acc*vmul); 2 f32 out.
// =====================================================================
template <int NTAPS, int EPI>
__global__ __launch_bounds__(512, 1)
void gg_kernel(const u16* __restrict__ src, const u16* __restrict__ WT,
               const int* __restrict__ nbr, u16* __restrict__ outb,
               float* __restrict__ outf, const u16* __restrict__ vmul) {
  __shared__ uint4 lds[8192];          // 128 KB: four 32 KB stage buffers
  char* const base = (char*)lds;
  char* const bufs[4] = {base, base + 32768, base + 65536, base + 98304};

  const int tid  = threadIdx.x;
  const int lane = tid & 63;
  const int wv   = tid >> 6;           // 0..7
  const int wr   = wv >> 1, wc = wv & 1;   // 4x2 compute grid
  const int lsub = lane >> 4, lm = lane & 15;
  const int r8   = lane >> 3;          // DMA: row/col within instr (0..7)
  const int cs8  = lane & 7;           // DMA: chunk slot (0..7, 16 B)
  const int row0 = blockIdx.x * 128;

  f32x4 acc[2][4];
#pragma unroll
  for (int i = 0; i < 2; i++)
#pragma unroll
    for (int j = 0; j < 4; j++) acc[i][j] = (f32x4)(0.0f);

  // ---- idx loads (asm: invisible to waitcnt pass; retired by the manual
  // waits exactly 3 stages before use; ~88 VGPR total -> no allocator risk)
  auto loadIdx = [&](int (&d)[2], int st) {
    const int tp = st < NTAPS ? st : st - NTAPS;
#pragma unroll
    for (int j = 0; j < 2; j++) {
      const int gr = row0 + wv * 16 + j * 8 + r8;
      const int* p = nbr + (size_t)gr * NTAPS + tp;
      asm volatile("global_load_dword %0, %1, off"
                   : "=v"(d[j]) : "v"(p) : "memory");
    }
  };

  // ---- A half-stage for stage st (2 DMA/wave)
  auto stageA = [&](char* buf, const int (&id)[2], int st) {
    const int h = st < NTAPS ? 0 : 1;
#pragma unroll
    for (int j = 0; j < 2; j++) {
      const char* gp = (const char*)src + ((size_t)(unsigned)id[j] << 8)
                     + (h << 7) + ((cs8 ^ r8) << 4);
      g2l16(gp, buf + (wv * 16 + j * 8) * 128);
    }
  };

  // ---- B half-stage for stage st (2 DMA/wave)
  auto stageB = [&](char* buf, int st) {
    const int tp = st < NTAPS ? st : st - NTAPS;
    const int h = st < NTAPS ? 0 : 1;
    const char* wt = (const char*)WT + ((size_t)tp << 15) + (h << 7);
#pragma unroll
    for (int j = 0; j < 2; j++) {
      const int col = wv * 16 + j * 8 + r8;
      g2l16(wt + ((size_t)col << 8) + ((cs8 ^ r8) << 4),
            buf + 16384 + (wv * 16 + j * 8) * 128);
    }
  };

  // ---- one stage of MFMA: A and B both from LDS (no vmem-reg consumers).
  // Wave tile 32x64: per kk-step 2 af + 4 bg = 6 ds_read_b128, 8 MFMA.
  auto computeS = [&](const char* buf) {
#pragma unroll
    for (int kk2 = 0; kk2 < 2; kk2++) {
      bfrag af[2], bg[4];
#pragma unroll
      for (int rt = 0; rt < 2; rt++) {
        const int row = wr * 32 + rt * 16 + lm;
        af[rt] = *(const bfrag*)(buf + row * 128
                                 + (((kk2 * 4 + lsub) ^ (row & 7)) << 4));
      }
#pragma unroll
      for (int ct = 0; ct < 4; ct++) {
        const int col = wc * 64 + ct * 16 + lm;
        bg[ct] = *(const bfrag*)(buf + 16384 + col * 128
                                 + (((kk2 * 4 + lsub) ^ (col & 7)) << 4));
      }
#pragma unroll
      for (int rt = 0; rt < 2; rt++)
#pragma unroll
        for (int ct = 0; ct < 4; ct++)
          acc[rt][ct] = __builtin_amdgcn_mfma_f32_16x16x32_bf16(
              af[rt], bg[ct], acc[rt][ct], 0, 0, 0);
    }
  };

  if constexpr (NTAPS == 1) {
    // dense 1x1: own rows from registers, B halves into bufs 0/1, one drain.
    // aR[h][rt][kk2]: lane's 16B of row (row0+wr*32+rt*16+lm) at byte
    // h*128 + kk2*64 + lsub*16.
    bfrag aR[2][2][2];
#pragma unroll
    for (int rt = 0; rt < 2; rt++) {
      const char* rb = (const char*)src
          + (size_t)(row0 + wr * 32 + rt * 16 + lm) * 256 + lsub * 16;
      aR[0][rt][0] = *(const bfrag*)(rb);
      aR[0][rt][1] = *(const bfrag*)(rb + 64);
      aR[1][rt][0] = *(const bfrag*)(rb + 128);
      aR[1][rt][1] = *(const bfrag*)(rb + 192);
    }
    stageB(bufs[0], 0);                  // tap0 h0
    stageB(bufs[1], 1);                  // tap0 h1
    GG_WB(0);
#pragma unroll
    for (int h = 0; h < 2; h++) {
      const char* buf = bufs[h];
#pragma unroll
      for (int kk2 = 0; kk2 < 2; kk2++) {
        bfrag bg[4];
#pragma unroll
        for (int ct = 0; ct < 4; ct++) {
          const int col = wc * 64 + ct * 16 + lm;
          bg[ct] = *(const bfrag*)(buf + 16384 + col * 128
                                   + (((kk2 * 4 + lsub) ^ (col & 7)) << 4));
        }
#pragma unroll
        for (int rt = 0; rt < 2; rt++)
#pragma unroll
          for (int ct = 0; ct < 4; ct++)
            acc[rt][ct] = __builtin_amdgcn_mfma_f32_16x16x32_bf16(
                aR[h][rt][kk2], bg[ct], acc[rt][ct], 0, 0, 0);
      }
    }
  } else {
    constexpr int S = 2 * NTAPS;         // stages; N odd -> S-6 % 4 == 0
    int idr[4][2], ip0[2], ip1[2], ip2[2];
    // ---- prologue: idx(0..2) -> drain -> groups G(-3),G(-2),G(-1)
    loadIdx(ip0, 0); loadIdx(ip1, 1); loadIdx(ip2, 2);   // 6 ops
    GG_W(0);
    stageA(bufs[0], ip0, 0); stageB(bufs[0], 0); loadIdx(idr[1], 3);
    stageA(bufs[1], ip1, 1); stageB(bufs[1], 1); loadIdx(idr[2], 4);
    stageA(bufs[2], ip2, 2); stageB(bufs[2], 2); loadIdx(idr[3], 5);
    // FIFO = 18 = three 6-op groups; steady invariant holds from stage 0.

    // ---- main: stage s consumes idr[(s+1)&3] (idx of stage s+3, loaded at
    // s-3), loads idr[s&3] <- idx(stage s+6). One wait per stage.
#define GG_SUB(p)                                                          \
    GG_WB(12);                                                             \
    stageA(bufs[((p) + 3) & 3], idr[((p) + 1) & 3], s + (p) + 3);          \
    stageB(bufs[((p) + 3) & 3], s + (p) + 3);                              \
    loadIdx(idr[(p) & 3], s + (p) + 6);                                    \
    computeS(bufs[(p) & 3]);

#pragma unroll 1
    for (int s = 0; s < S - 6; s += 4) {
      GG_SUB(0)
      GG_SUB(1)
      GG_SUB(2)
      GG_SUB(3)
    }
#undef GG_SUB

    // ---- tail: stages S-6..S-1 (phases 0,1,2,3,0,1), no idx loads.
    // idx slots: S%4==2 -> idx(S-3)@slot1, idx(S-2)@slot2, idx(S-1)@slot3.
    GG_WB(12);
    stageA(bufs[3], idr[1], S - 3); stageB(bufs[3], S - 3);
    computeS(bufs[0]);                   // stage S-6
    GG_WB(10);
    stageA(bufs[0], idr[2], S - 2); stageB(bufs[0], S - 2);
    computeS(bufs[1]);                   // stage S-5
    GG_WB(8);
    stageA(bufs[1], idr[3], S - 1); stageB(bufs[1], S - 1);
    computeS(bufs[2]);                   // stage S-4
    GG_WB(8);
    computeS(bufs[3]);                   // stage S-3
    GG_WB(4);
    computeS(bufs[0]);                   // stage S-2
    GG_WB(0);
    computeS(bufs[1]);                   // stage S-1
  }

  // ---- epilogue write. C/D: col = lane&15, row = lsub*4 + reg.
#pragma unroll
  for (int rt = 0; rt < 2; rt++) {
    const int rowb = row0 + wr * 32 + rt * 16 + lsub * 4;
#pragma unroll
    for (int ct = 0; ct < 4; ct++) {
      const int c = wc * 64 + ct * 16 + lm;
#pragma unroll
      for (int reg = 0; reg < 4; reg++) {
        const size_t off = (size_t)(rowb + reg) * C + c;
        const float v = acc[rt][ct][reg];
        if (EPI == 0)      outb[off] = f2b(v);
        else if (EPI == 1) outb[off] = f2b(v * b2f(vmul[off]));
        else               outf[off] = v;
      }
    }
  }
}

// ---- f32 -> bf16 bulk convert (for x) ------------------------------------
__global__ __launch_bounds__(256)
void cvt_kernel(const float* __restrict__ x, u16* __restrict__ xb) {
  const int i = (blockIdx.x * 256 + threadIdx.x) * 4;
  const float4 v = *(const float4*)(x + i);
  ushort4 o;
  o.x = f2b(v.x); o.y = f2b(v.y); o.z = f2b(v.z); o.w = f2b(v.w);
  *(ushort4*)(xb + i) = o;
}

// ---- weights: f32 [..,Cin,Cout] -> bf16 [..,Cout,Cin] --------------------
__global__ __launch_bounds__(256)
void wt_kernel(const float* __restrict__ W5, const float* __restrict__ W31,
               const float* __restrict__ W32, const float* __restrict__ Wa1,
               const float* __restrict__ Wv1,
               u16* __restrict__ T5, u16* __restrict__ T31, u16* __restrict__ T32,
               u16* __restrict__ Ta1, u16* __restrict__ Tv1) {
  const int b = blockIdx.x;
  const float* w;
  u16* o;
  if (b < 125)       { w = W5  + (size_t)b * 16384;         o = T5  + (size_t)b * 16384; }
  else if (b < 152)  { w = W31 + (size_t)(b - 125) * 16384; o = T31 + (size_t)(b - 125) * 16384; }
  else if (b < 179)  { w = W32 + (size_t)(b - 152) * 16384; o = T32 + (size_t)(b - 152) * 16384; }
  else if (b == 179) { w = Wa1; o = Ta1; }
  else               { w = Wv1; o = Tv1; }
  __shared__ u16 tile[128 * 129];
  for (int i = threadIdx.x; i < C * C; i += 256)
    tile[(i & 127) * 129 + (i >> 7)] = f2b(w[i]);
  __syncthreads();
  for (int i = threadIdx.x; i < C * C; i += 256)
    o[i] = tile[(i >> 7) * 129 + (i & 127)];
}

// ---- BN partials (f32): block b owns rows [b*128, +128) ------------------
__global__ __launch_bounds__(256)
void bnp_kernel(const float* __restrict__ t, float* __restrict__ psum,
                float* __restrict__ psq) {
  const int b = blockIdx.x;
  const int c = threadIdx.x & 127;
  const int h = threadIdx.x >> 7;
  const float* p = t + (size_t)(b * 128 + h * 64) * C + c;
  float s = 0.f, q = 0.f;
#pragma unroll 8
  for (int j = 0; j < 64; j++) {
    const float v = p[(size_t)j * C];
    s += v; q += v * v;
  }
  __shared__ float ls[256], lq[256];
  ls[threadIdx.x] = s; lq[threadIdx.x] = q;
  __syncthreads();
  if (h == 0) {
    psum[b * 128 + c] = ls[c] + ls[c + 128];
    psq[b * 128 + c]  = lq[c] + lq[c + 128];
  }
}

// ---- bnfin: block c reduces 256 partials (parallel) ----------------------
__global__ __launch_bounds__(256)
void bnfin_kernel(const float* __restrict__ psum, const float* __restrict__ psq,
                  const float* __restrict__ gamma, const float* __restrict__ beta,
                  float* __restrict__ scale, float* __restrict__ shift) {
  const int c = blockIdx.x;
  const int t = threadIdx.x;
  float s = psum[(size_t)t * 128 + c];
  float q = psq[(size_t)t * 128 + c];
#pragma unroll
  for (int o = 32; o > 0; o >>= 1) {
    s += __shfl_down(s, o);
    q += __shfl_down(q, o);
  }
  __shared__ float ls[4], lq[4];
  if ((t & 63) == 0) { ls[t >> 6] = s; lq[t >> 6] = q; }
  __syncthreads();
  if (t == 0) {
    s = ls[0] + ls[1] + ls[2] + ls[3];
    q = lq[0] + lq[1] + lq[2] + lq[3];
    const float mean = s * (1.0f / NPTS);
    const float var  = q * (1.0f / NPTS) - mean * mean;
    const float sc   = rsqrtf(var + EPS) * gamma[c];
    scale[c] = sc;
    shift[c] = beta[c] - mean * sc;
  }
}

// ---- ew1: o = t*sc+sh + x; res=bf16(o); h=bf16(relu o) -------------------
__global__ __launch_bounds__(256)
void ew1_kernel(const float* __restrict__ t, const float* __restrict__ x,
                const float* __restrict__ scale, const float* __restrict__ shift,
                u16* __restrict__ res, u16* __restrict__ h) {
  const int i = blockIdx.x * 256 + threadIdx.x;
  const int c = i & 127;
  const float o = t[i] * scale[c] + shift[c] + x[i];
  res[i] = f2b(o);
  h[i] = f2b(o < 0.f ? 0.f : o);
}

// ---- ew2: y = relu(t2*sc+sh + res) -> f32 d_out --------------------------
__global__ __launch_bounds__(256)
void ew2_kernel(const float* __restrict__ t2, const u16* __restrict__ res,
                const float* __restrict__ scale, const float* __restrict__ shift,
                float* __restrict__ y) {
  const int i = blockIdx.x * 256 + threadIdx.x;
  const int c = i & 127;
  const float o = t2[i] * scale[c] + shift[c] + b2f(res[i]);
  y[i] = o < 0.f ? 0.f : o;
}

// =====================================================================
extern "C" void kernel_launch(void* const* d_in, const int* in_sizes, int n_in,
                              void* d_out, int out_size, void* d_ws, size_t ws_size,
                              hipStream_t stream) {
  (void)in_sizes; (void)n_in; (void)out_size; (void)ws_size;

  const float* x   = (const float*)d_in[0];
  const float* Wa1 = (const float*)d_in[1];
  const float* Wv1 = (const float*)d_in[2];
  const float* W5  = (const float*)d_in[3];
  const float* W31 = (const float*)d_in[4];
  const float* W32 = (const float*)d_in[5];
  const float* g1  = (const float*)d_in[6];
  const float* b1  = (const float*)d_in[7];
  const float* g2  = (const float*)d_in[8];
  const float* b2  = (const float*)d_in[9];
  const int* nbr5  = (const int*)d_in[10];
  const int* nbr3a = (const int*)d_in[11];
  const int* nbr3b = (const int*)d_in[12];

  // ---- workspace (~39.8 MB) ----
  char* w = (char*)d_ws;
  u16* WT5  = (u16*)w; w += 4096000;
  u16* WT31 = (u16*)w; w += 884736;
  u16* WT32 = (u16*)w; w += 884736;
  u16* WTa1 = (u16*)w; w += 32768;
  u16* WTv1 = (u16*)w; w += 32768;
  char* AV  = w;       w += 16777216;          // a | v ; later t/t2 (f32)
  u16*   a_b = (u16*)AV;
  u16*   v_b = (u16*)(AV + 8388608);
  float* tf  = (float*)AV;
  u16* g_b  = (u16*)w; w += 8388608;           // g ; later res (bf16)
  u16* h_b  = (u16*)w; w += 8388608;           // xb first, then h (bf16)
  u16* xb   = h_b;                             // alias: xb dead before ew1
  float* psum = (float*)w; w += 131072;
  float* psq  = (float*)w; w += 131072;
  float* sc1  = (float*)w; w += 512;
  float* sh1  = (float*)w; w += 512;
  float* sc2  = (float*)w; w += 512;
  float* sh2  = (float*)w; w += 512;

  const dim3 B512(512), GG(NPTS / 128), B256(256), GBN(256), GEW(NPTS * C / 256);
  float* yout = (float*)d_out;

  cvt_kernel<<<dim3(NPTS * C / 1024), B256, 0, stream>>>(x, xb);
  wt_kernel<<<dim3(181), B256, 0, stream>>>(W5, W31, W32, Wa1, Wv1,
                                            WT5, WT31, WT32, WTa1, WTv1);

  // a = xb @ Wa1 ; v = xb @ Wv1
  gg_kernel<1, 0><<<GG, B512, 0, stream>>>(xb, WTa1, nullptr, a_b, nullptr, nullptr);
  gg_kernel<1, 0><<<GG, B512, 0, stream>>>(xb, WTv1, nullptr, v_b, nullptr, nullptr);

  // g = gather125(a)@W5 * v
  gg_kernel<125, 1><<<GG, B512, 0, stream>>>(a_b, WT5, nbr5, g_b, nullptr, v_b);

  // t = gather27(g)@W31 -> f32 over AV (a,v dead)
  gg_kernel<27, 2><<<GG, B512, 0, stream>>>(g_b, WT31, nbr3a, nullptr, tf, nullptr);
  bnp_kernel<<<GBN, B256, 0, stream>>>(tf, psum, psq);
  bnfin_kernel<<<dim3(128), B256, 0, stream>>>(psum, psq, g1, b1, sc1, sh1);
  ew1_kernel<<<GEW, B256, 0, stream>>>(tf, x, sc1, sh1, g_b, h_b);   // res->g_b, h->h_b (xb dead)

  // t2 = gather27(h)@W32 -> f32 over AV (t dead)
  gg_kernel<27, 2><<<GG, B512, 0, stream>>>(h_b, WT32, nbr3b, nullptr, tf, nullptr);
  bnp_kernel<<<GBN, B256, 0, stream>>>(tf, psum, psq);
  bnfin_kernel<<<dim3(128), B256, 0, stream>>>(psum, psq, g2, b2, sc2, sh2);
  ew2_kernel<<<GEW, B256, 0, stream>>>(tf, g_b, sc2, sh2, yout);
}

// Round 10
// 376.009 us; speedup vs baseline: 1.2978x; 1.0023x over previous
//
#include <hip/hip_runtime.h>
#include <stdint.h>

// MinkFormerBlock on MI355X (gfx950). I/O: f32 in, f32 out (verified R8).
// R23: K-split wave pairs -> 64x64 tiles, staging untouched. R22 confirmed
// the LDS-BW model (96 b128/CU-stage x 12cyc = 1152 ~= 70% of the 1635cyc
// stage; MfmaUtil 29->35.5, 203->170us). LDS reads scale with (rows+cols)
// per wave tile: 32x64 -> 768 sum/CU; 64x64 -> 512 (0.67x). Getting 64x64
// WITHOUT touching the proven staging/ledger: waves w and w+4 pair on one
// 64x64 tile; wave computes only kk2 = wv>>2 (K 0-31 or 32-63 of each
// stage) into private acc[4][4]; partials summed ONCE at epilogue via a
// 64KB LDS exchange (ring buffers reused, one-time). Per wave per stage:
// 4 A + 4 B = 8 b128 (was 12), 16 MFMA (unchanged) -> 64 b128/CU-stage,
// ~770cyc LDS, stage ~1250cyc predicted. Dense path unified (identity idx,
// LDS-staged A, same reduction).
// R21/R22 recap (unchanged here): all-LDS deep pipeline (no register-load
// consumers in loop -> counted vmcnt depth real), 8-wave 128x128 blocks,
// channel-phase stage order (stage=(tap,half) -> gather L2-resident, FETCH
// 170MB), 4-deep 32KB ring, 6-op groups (A2+B2+idx2), one
// vmcnt(12)+lgkm(0)+barrier per stage, asm idx retired 3 stages pre-use.
// Ledger FIFO-traced: steady 12; tail 12,10,8,8,4,0. Zero-conflict
// 128B-stride swizzled LDS layout (measured 0).
//
//   cvt:       xb = bf16(x)            (aliases h_b, dead until ew1)
//   wt:        WT* = bf16(W^T)  [tap][Cout][Cin]
//   gg<1,0>:   a = xb @ Wa1 ; v = xb @ Wv1     (bf16)
//   gg<125,1>: g = gather(a,nbr5)@W5 * v       (bf16, fused gate)
//   gg<27,2>:  t = gather(g,nbr3a)@W31         (f32)
//   bn+fin -> sc1,sh1 ; ew1: res=bf16->g_b, h=bf16(relu)->h_b
//   gg<27,2>:  t2 = gather(h,nbr3b)@W32        (f32)
//   bn+fin -> sc2,sh2 ; ew2: d_out = relu(t2*sc+sh + res)  (f32)

#define NPTS 32768
#define C 128
#define EPS 1e-5f

typedef unsigned short u16;
using bfrag = __attribute__((ext_vector_type(8))) short;   // 8 bf16 = 4 VGPRs
using f32x4 = __attribute__((ext_vector_type(4))) float;

__device__ __forceinline__ float b2f(u16 u) {
  union { unsigned int i; float f; } x;
  x.i = ((unsigned int)u) << 16;
  return x.f;
}
__device__ __forceinline__ u16 f2b(float f) {
  union { float f; unsigned int i; } x;
  x.f = f;
  unsigned int r = x.i + 0x7FFFu + ((x.i >> 16) & 1u);   // RNE
  return (u16)(r >> 16);
}

// async global->LDS, 16 B per lane; LDS dest is wave-uniform base + lane*16.
__device__ __forceinline__ void g2l16(const void* g, void* l) {
  __builtin_amdgcn_global_load_lds(
      (const __attribute__((address_space(1))) unsigned int*)g,
      (__attribute__((address_space(3))) unsigned int*)l,
      16, 0, 0);
}

#define GG_W(N)                                                            \
  asm volatile("s_waitcnt vmcnt(" #N ")" ::: "memory");                    \
  __builtin_amdgcn_sched_barrier(0)

// counted vmcnt (own stage-group certified BEFORE barrier) + lgkm drain
// (prev stage's ds_reads, WAR safety) + block barrier + sched fence.
#define GG_WB(N)                                                           \
  asm volatile("s_waitcnt vmcnt(" #N ") lgkmcnt(0)" ::: "memory");         \
  __builtin_amdgcn_s_barrier();                                            \
  __builtin_amdgcn_sched_barrier(0)

// =====================================================================
// Gather-GEMM. Block = 128x128 output, 512 threads, 8 waves. Compute: 4
// tile-pairs -- pair p = (wv&3) owns rows [(p>>1)*64,+64) x cols
// [(p&1)*64,+64); wave computes kk2 = wv>>2 only; acc[4][4] f32x4 partial;
// 16 MFMA/stage/wave; 8 ds_read_b128/stage/wave. Partials reduced once at
// epilogue (waves 4-7 -> LDS 64KB -> waves 0-3 add, write C).
// Stage s in [0, 2*NTAPS): tap = s<N?s:s-N, half = s<N?0:1 (channel-phase).
// LDS ring: buf[s&3] = A-half [128 rows][128B] + B-half [128 cols][128B].
// Stage group (issued at stage s-3, by wv -- barrier decouples): A 2 g2l16
// (rows wv*16+j*8+r8, chunk cs8^r8 of src+id*256+h*128), B 2 g2l16 (cols
// likewise of WT+tap*32K+h*128), idx 2 asm global_load_dword (for stage
// s+6, consumed s+3). Reads at slot (kk2*4+lsub)^(row&7): zero-conflict.
// EPI: 0 bf16 out; 1 bf16(acc*vmul); 2 f32 out.
// =====================================================================
template <int NTAPS, int EPI>
__global__ __launch_bounds__(512, 1)
void gg_kernel(const u16* __restrict__ src, const u16* __restrict__ WT,
               const int* __restrict__ nbr, u16* __restrict__ outb,
               float* __restrict__ outf, const u16* __restrict__ vmul) {
  __shared__ uint4 lds[8192];          // 128 KB: four 32 KB stage buffers
  char* const base = (char*)lds;
  char* const bufs[4] = {base, base + 32768, base + 65536, base + 98304};

  const int tid  = threadIdx.x;
  const int lane = tid & 63;
  const int wv   = tid >> 6;           // 0..7
  const int wq   = wv & 3;             // tile-pair id
  const int wr   = wq >> 1, wc = wq & 1;   // 2x2 grid of 64x64 tiles
  const int kk2w = wv >> 2;            // K-chunk owned by this wave (0/1)
  const int lsub = lane >> 4, lm = lane & 15;
  const int r8   = lane >> 3;          // DMA: row/col within instr (0..7)
  const int cs8  = lane & 7;           // DMA: chunk slot (0..7, 16 B)
  const int row0 = blockIdx.x * 128;

  f32x4 acc[4][4];
#pragma unroll
  for (int i = 0; i < 4; i++)
#pragma unroll
    for (int j = 0; j < 4; j++) acc[i][j] = (f32x4)(0.0f);

  // ---- idx loads (asm: invisible to waitcnt pass; retired by the manual
  // waits exactly 3 stages before use)
  auto loadIdx = [&](int (&d)[2], int st) {
    const int tp = st < NTAPS ? st : st - NTAPS;
#pragma unroll
    for (int j = 0; j < 2; j++) {
      const int gr = row0 + wv * 16 + j * 8 + r8;
      const int* p = nbr + (size_t)gr * NTAPS + tp;
      asm volatile("global_load_dword %0, %1, off"
                   : "=v"(d[j]) : "v"(p) : "memory");
    }
  };

  // ---- A half-stage for stage st (2 DMA/wave)
  auto stageA = [&](char* buf, const int (&id)[2], int st) {
    const int h = st < NTAPS ? 0 : 1;
#pragma unroll
    for (int j = 0; j < 2; j++) {
      const char* gp = (const char*)src + ((size_t)(unsigned)id[j] << 8)
                     + (h << 7) + ((cs8 ^ r8) << 4);
      g2l16(gp, buf + (wv * 16 + j * 8) * 128);
    }
  };

  // ---- B half-stage for stage st (2 DMA/wave)
  auto stageB = [&](char* buf, int st) {
    const int tp = st < NTAPS ? st : st - NTAPS;
    const int h = st < NTAPS ? 0 : 1;
    const char* wt = (const char*)WT + ((size_t)tp << 15) + (h << 7);
#pragma unroll
    for (int j = 0; j < 2; j++) {
      const int col = wv * 16 + j * 8 + r8;
      g2l16(wt + ((size_t)col << 8) + ((cs8 ^ r8) << 4),
            buf + 16384 + (wv * 16 + j * 8) * 128);
    }
  };

  // ---- one stage of MFMA (K-split): this wave does only kk2 = kk2w.
  // 64x64 tile: 4 af + 4 bg = 8 ds_read_b128, 16 MFMA.
  auto computeS = [&](const char* buf) {
    bfrag af[4], bg[4];
#pragma unroll
    for (int rt = 0; rt < 4; rt++) {
      const int row = wr * 64 + rt * 16 + lm;
      af[rt] = *(const bfrag*)(buf + row * 128
                               + (((kk2w * 4 + lsub) ^ (row & 7)) << 4));
    }
#pragma unroll
    for (int ct = 0; ct < 4; ct++) {
      const int col = wc * 64 + ct * 16 + lm;
      bg[ct] = *(const bfrag*)(buf + 16384 + col * 128
                               + (((kk2w * 4 + lsub) ^ (col & 7)) << 4));
    }
#pragma unroll
    for (int rt = 0; rt < 4; rt++)
#pragma unroll
      for (int ct = 0; ct < 4; ct++)
        acc[rt][ct] = __builtin_amdgcn_mfma_f32_16x16x32_bf16(
            af[rt], bg[ct], acc[rt][ct], 0, 0, 0);
  };

  if constexpr (NTAPS == 1) {
    // dense 1x1: identity indices, both halves staged, one drain, K-split
    int idv[2];
#pragma unroll
    for (int j = 0; j < 2; j++) idv[j] = row0 + wv * 16 + j * 8 + r8;
    stageA(bufs[0], idv, 0); stageB(bufs[0], 0);   // tap0 h0
    stageA(bufs[1], idv, 1); stageB(bufs[1], 1);   // tap0 h1
    GG_WB(0);
    computeS(bufs[0]);
    computeS(bufs[1]);
  } else {
    constexpr int S = 2 * NTAPS;         // stages; N odd -> S-6 % 4 == 0
    int idr[4][2], ip0[2], ip1[2], ip2[2];
    // ---- prologue: idx(0..2) -> drain -> groups G(-3),G(-2),G(-1)
    loadIdx(ip0, 0); loadIdx(ip1, 1); loadIdx(ip2, 2);   // 6 ops
    GG_W(0);
    stageA(bufs[0], ip0, 0); stageB(bufs[0], 0); loadIdx(idr[1], 3);
    stageA(bufs[1], ip1, 1); stageB(bufs[1], 1); loadIdx(idr[2], 4);
    stageA(bufs[2], ip2, 2); stageB(bufs[2], 2); loadIdx(idr[3], 5);
    // FIFO = 18 = three 6-op groups; steady invariant holds from stage 0.

    // ---- main: stage s consumes idr[(s+1)&3] (idx of stage s+3, loaded at
    // s-3), loads idr[s&3] <- idx(stage s+6). One wait per stage.
#define GG_SUB(p)                                                          \
    GG_WB(12);                                                             \
    stageA(bufs[((p) + 3) & 3], idr[((p) + 1) & 3], s + (p) + 3);          \
    stageB(bufs[((p) + 3) & 3], s + (p) + 3);                              \
    loadIdx(idr[(p) & 3], s + (p) + 6);                                    \
    computeS(bufs[(p) & 3]);

#pragma unroll 1
    for (int s = 0; s < S - 6; s += 4) {
      GG_SUB(0)
      GG_SUB(1)
      GG_SUB(2)
      GG_SUB(3)
    }
#undef GG_SUB

    // ---- tail: stages S-6..S-1 (phases 0,1,2,3,0,1), no idx loads.
    // idx slots: S%4==2 -> idx(S-3)@slot1, idx(S-2)@slot2, idx(S-1)@slot3.
    GG_WB(12);
    stageA(bufs[3], idr[1], S - 3); stageB(bufs[3], S - 3);
    computeS(bufs[0]);                   // stage S-6
    GG_WB(10);
    stageA(bufs[0], idr[2], S - 2); stageB(bufs[0], S - 2);
    computeS(bufs[1]);                   // stage S-5
    GG_WB(8);
    stageA(bufs[1], idr[3], S - 1); stageB(bufs[1], S - 1);
    computeS(bufs[2]);                   // stage S-4
    GG_WB(8);
    computeS(bufs[3]);                   // stage S-3
    GG_WB(4);
    computeS(bufs[0]);                   // stage S-2
    GG_WB(0);
    computeS(bufs[1]);                   // stage S-1
  }

  // ---- K-split reduction: waves 4-7 park partials in LDS (64 KB, ring
  // buffers dead after last computeS); waves 0-3 add partner's partial.
  asm volatile("s_waitcnt lgkmcnt(0)" ::: "memory");
  __builtin_amdgcn_s_barrier();          // all compute ds_reads done
  __builtin_amdgcn_sched_barrier(0);
  if (wv >= 4) {
    char* dst = base + (size_t)(wv - 4) * 16384 + lane * 16;
#pragma unroll
    for (int rt = 0; rt < 4; rt++)
#pragma unroll
      for (int ct = 0; ct < 4; ct++)
        *(f32x4*)(dst + (rt * 4 + ct) * 1024) = acc[rt][ct];
  }
  asm volatile("s_waitcnt lgkmcnt(0)" ::: "memory");
  __builtin_amdgcn_s_barrier();
  __builtin_amdgcn_sched_barrier(0);

  // ---- epilogue write by waves 0-3. C/D: col = lane&15, row = lsub*4+reg.
  if (wv < 4) {
    const char* psrc = base + (size_t)wv * 16384 + lane * 16;
#pragma unroll
    for (int rt = 0; rt < 4; rt++) {
      const int rowb = row0 + wr * 64 + rt * 16 + lsub * 4;
#pragma unroll
      for (int ct = 0; ct < 4; ct++) {
        const f32x4 part = *(const f32x4*)(psrc + (rt * 4 + ct) * 1024);
        const f32x4 v4 = acc[rt][ct] + part;
        const int c = wc * 64 + ct * 16 + lm;
#pragma unroll
        for (int reg = 0; reg < 4; reg++) {
          const size_t off = (size_t)(rowb + reg) * C + c;
          const float v = v4[reg];
          if (EPI == 0)      outb[off] = f2b(v);
          else if (EPI == 1) outb[off] = f2b(v * b2f(vmul[off]));
          else               outf[off] = v;
        }
      }
    }
  }
}

// ---- f32 -> bf16 bulk convert (for x) ------------------------------------
__global__ __launch_bounds__(256)
void cvt_kernel(const float* __restrict__ x, u16* __restrict__ xb) {
  const int i = (blockIdx.x * 256 + threadIdx.x) * 4;
  const float4 v = *(const float4*)(x + i);
  ushort4 o;
  o.x = f2b(v.x); o.y = f2b(v.y); o.z = f2b(v.z); o.w = f2b(v.w);
  *(ushort4*)(xb + i) = o;
}

// ---- weights: f32 [..,Cin,Cout] -> bf16 [..,Cout,Cin] --------------------
__global__ __launch_bounds__(256)
void wt_kernel(const float* __restrict__ W5, const float* __restrict__ W31,
               const float* __restrict__ W32, const float* __restrict__ Wa1,
               const float* __restrict__ Wv1,
               u16* __restrict__ T5, u16* __restrict__ T31, u16* __restrict__ T32,
               u16* __restrict__ Ta1, u16* __restrict__ Tv1) {
  const int b = blockIdx.x;
  const float* w;
  u16* o;
  if (b < 125)       { w = W5  + (size_t)b * 16384;         o = T5  + (size_t)b * 16384; }
  else if (b < 152)  { w = W31 + (size_t)(b - 125) * 16384; o = T31 + (size_t)(b - 125) * 16384; }
  else if (b < 179)  { w = W32 + (size_t)(b - 152) * 16384; o = T32 + (size_t)(b - 152) * 16384; }
  else if (b == 179) { w = Wa1; o = Ta1; }
  else               { w = Wv1; o = Tv1; }
  __shared__ u16 tile[128 * 129];
  for (int i = threadIdx.x; i < C * C; i += 256)
    tile[(i & 127) * 129 + (i >> 7)] = f2b(w[i]);
  __syncthreads();
  for (int i = threadIdx.x; i < C * C; i += 256)
    o[i] = tile[(i >> 7) * 129 + (i & 127)];
}

// ---- BN partials (f32): block b owns rows [b*128, +128) ------------------
__global__ __launch_bounds__(256)
void bnp_kernel(const float* __restrict__ t, float* __restrict__ psum,
                float* __restrict__ psq) {
  const int b = blockIdx.x;
  const int c = threadIdx.x & 127;
  const int h = threadIdx.x >> 7;
  const float* p = t + (size_t)(b * 128 + h * 64) * C + c;
  float s = 0.f, q = 0.f;
#pragma unroll 8
  for (int j = 0; j < 64; j++) {
    const float v = p[(size_t)j * C];
    s += v; q += v * v;
  }
  __shared__ float ls[256], lq[256];
  ls[threadIdx.x] = s; lq[threadIdx.x] = q;
  __syncthreads();
  if (h == 0) {
    psum[b * 128 + c] = ls[c] + ls[c + 128];
    psq[b * 128 + c]  = lq[c] + lq[c + 128];
  }
}

// ---- bnfin: block c reduces 256 partials (parallel) ----------------------
__global__ __launch_bounds__(256)
void bnfin_kernel(const float* __restrict__ psum, const float* __restrict__ psq,
                  const float* __restrict__ gamma, const float* __restrict__ beta,
                  float* __restrict__ scale, float* __restrict__ shift) {
  const int c = blockIdx.x;
  const int t = threadIdx.x;
  float s = psum[(size_t)t * 128 + c];
  float q = psq[(size_t)t * 128 + c];
#pragma unroll
  for (int o = 32; o > 0; o >>= 1) {
    s += __shfl_down(s, o);
    q += __shfl_down(q, o);
  }
  __shared__ float ls[4], lq[4];
  if ((t & 63) == 0) { ls[t >> 6] = s; lq[t >> 6] = q; }
  __syncthreads();
  if (t == 0) {
    s = ls[0] + ls[1] + ls[2] + ls[3];
    q = lq[0] + lq[1] + lq[2] + lq[3];
    const float mean = s * (1.0f / NPTS);
    const float var  = q * (1.0f / NPTS) - mean * mean;
    const float sc   = rsqrtf(var + EPS) * gamma[c];
    scale[c] = sc;
    shift[c] = beta[c] - mean * sc;
  }
}

// ---- ew1: o = t*sc+sh + x; res=bf16(o); h=bf16(relu o) -------------------
__global__ __launch_bounds__(256)
void ew1_kernel(const float* __restrict__ t, const float* __restrict__ x,
                const float* __restrict__ scale, const float* __restrict__ shift,
                u16* __restrict__ res, u16* __restrict__ h) {
  const int i = blockIdx.x * 256 + threadIdx.x;
  const int c = i & 127;
  const float o = t[i] * scale[c] + shift[c] + x[i];
  res[i] = f2b(o);
  h[i] = f2b(o < 0.f ? 0.f : o);
}

// ---- ew2: y = relu(t2*sc+sh + res) -> f32 d_out --------------------------
__global__ __launch_bounds__(256)
void ew2_kernel(const float* __restrict__ t2, const u16* __restrict__ res,
                const float* __restrict__ scale, const float* __restrict__ shift,
                float* __restrict__ y) {
  const int i = blockIdx.x * 256 + threadIdx.x;
  const int c = i & 127;
  const float o = t2[i] * scale[c] + shift[c] + b2f(res[i]);
  y[i] = o < 0.f ? 0.f : o;
}

// =====================================================================
extern "C" void kernel_launch(void* const* d_in, const int* in_sizes, int n_in,
                              void* d_out, int out_size, void* d_ws, size_t ws_size,
                              hipStream_t stream) {
  (void)in_sizes; (void)n_in; (void)out_size; (void)ws_size;

  const float* x   = (const float*)d_in[0];
  const float* Wa1 = (const float*)d_in[1];
  const float* Wv1 = (const float*)d_in[2];
  const float* W5  = (const float*)d_in[3];
  const float* W31 = (const float*)d_in[4];
  const float* W32 = (const float*)d_in[5];
  const float* g1  = (const float*)d_in[6];
  const float* b1  = (const float*)d_in[7];
  const float* g2  = (const float*)d_in[8];
  const float* b2  = (const float*)d_in[9];
  const int* nbr5  = (const int*)d_in[10];
  const int* nbr3a = (const int*)d_in[11];
  const int* nbr3b = (const int*)d_in[12];

  // ---- workspace (~39.8 MB) ----
  char* w = (char*)d_ws;
  u16* WT5  = (u16*)w; w += 4096000;
  u16* WT31 = (u16*)w; w += 884736;
  u16* WT32 = (u16*)w; w += 884736;
  u16* WTa1 = (u16*)w; w += 32768;
  u16* WTv1 = (u16*)w; w += 32768;
  char* AV  = w;       w += 16777216;          // a | v ; later t/t2 (f32)
  u16*   a_b = (u16*)AV;
  u16*   v_b = (u16*)(AV + 8388608);
  float* tf  = (float*)AV;
  u16* g_b  = (u16*)w; w += 8388608;           // g ; later res (bf16)
  u16* h_b  = (u16*)w; w += 8388608;           // xb first, then h (bf16)
  u16* xb   = h_b;                             // alias: xb dead before ew1
  float* psum = (float*)w; w += 131072;
  float* psq  = (float*)w; w += 131072;
  float* sc1  = (float*)w; w += 512;
  float* sh1  = (float*)w; w += 512;
  float* sc2  = (float*)w; w += 512;
  float* sh2  = (float*)w; w += 512;

  const dim3 B512(512), GG(NPTS / 128), B256(256), GBN(256), GEW(NPTS * C / 256);
  float* yout = (float*)d_out;

  cvt_kernel<<<dim3(NPTS * C / 1024), B256, 0, stream>>>(x, xb);
  wt_kernel<<<dim3(181), B256, 0, stream>>>(W5, W31, W32, Wa1, Wv1,
                                            WT5, WT31, WT32, WTa1, WTv1);

  // a = xb @ Wa1 ; v = xb @ Wv1
  gg_kernel<1, 0><<<GG, B512, 0, stream>>>(xb, WTa1, nullptr, a_b, nullptr, nullptr);
  gg_kernel<1, 0><<<GG, B512, 0, stream>>>(xb, WTv1, nullptr, v_b, nullptr, nullptr);

  // g = gather125(a)@W5 * v
  gg_kernel<125, 1><<<GG, B512, 0, stream>>>(a_b, WT5, nbr5, g_b, nullptr, v_b);

  // t = gather27(g)@W31 -> f32 over AV (a,v dead)
  gg_kernel<27, 2><<<GG, B512, 0, stream>>>(g_b, WT31, nbr3a, nullptr, tf, nullptr);
  bnp_kernel<<<GBN, B256, 0, stream>>>(tf, psum, psq);
  bnfin_kernel<<<dim3(128), B256, 0, stream>>>(psum, psq, g1, b1, sc1, sh1);
  ew1_kernel<<<GEW, B256, 0, stream>>>(tf, x, sc1, sh1, g_b, h_b);   // res->g_b, h->h_b (xb dead)

  // t2 = gather27(h)@W32 -> f32 over AV (t dead)
  gg_kernel<27, 2><<<GG, B512, 0, stream>>>(h_b, WT32, nbr3b, nullptr, tf, nullptr);
  bnp_kernel<<<GBN, B256, 0, stream>>>(tf, psum, psq);
  bnfin_kernel<<<dim3(128), B256, 0, stream>>>(psum, psq, g2, b2, sc2, sh2);
  ew2_kernel<<<GEW, B256, 0, stream>>>(tf, g_b, sc2, sh2, yout);
}

// Round 11
// 372.213 us; speedup vs baseline: 1.3111x; 1.0102x over previous
//
#include <hip/hip_runtime.h>
#include <stdint.h>

// MinkFormerBlock on MI355X (gfx950). I/O: f32 in, f32 out (verified R8).
// R24: R23 + T5 s_setprio around the MFMA cluster. R23 landed -5% (162.6us,
// MfmaUtil 36.8) -- LDS-read count dropped 96->64 b128/CU-stage but stage
// only 1635->1560cyc; residual = reads ~770 + DMA-writes ~300 + MFMA ~160
// + ~500cyc sync overhead. Context: gg<125> = 825 TF effective = the known
// ~900TF/37% ceiling of the 2-barrier-per-K-step plain-HIP GEMM structure.
// Of the 8-phase stack (T2 swizzle: have, conflict-free; T3/T4 counted
// vmcnt: have) only T5 setprio is unapplied. Prereq (wave role-diversity
// per phase) holds: DMA-issue segment vs ds_read+MFMA cluster. m218b/m224:
// +21-39% on counted-vmcnt structures; ~0 on lockstep. Change: setprio(1)
// before the MFMA double-loop in computeS, setprio(0) after (m201
// placement). Everything else byte-identical to R23 for attribution.
// R23 recap: K-split wave pairs (64x64 tiles, wave does kk2=wv>>2 only,
// partials summed once at epilogue via LDS); all-LDS deep pipeline; 8-wave
// 128x128 blocks; channel-phase stage order (gather L2-resident, FETCH
// 170MB); 4-deep 32KB ring; 6-op groups (A2+B2+idx2); one
// vmcnt(12)+lgkm(0)+barrier per stage; asm idx retired 3 stages pre-use.
// Ledger FIFO-traced: steady 12; tail 12,10,8,8,4,0. Zero-conflict
// 128B-stride swizzled LDS layout (measured 0).
//
//   cvt:       xb = bf16(x)            (aliases h_b, dead until ew1)
//   wt:        WT* = bf16(W^T)  [tap][Cout][Cin]
//   gg<1,0>:   a = xb @ Wa1 ; v = xb @ Wv1     (bf16)
//   gg<125,1>: g = gather(a,nbr5)@W5 * v       (bf16, fused gate)
//   gg<27,2>:  t = gather(g,nbr3a)@W31         (f32)
//   bn+fin -> sc1,sh1 ; ew1: res=bf16->g_b, h=bf16(relu)->h_b
//   gg<27,2>:  t2 = gather(h,nbr3b)@W32        (f32)
//   bn+fin -> sc2,sh2 ; ew2: d_out = relu(t2*sc+sh + res)  (f32)

#define NPTS 32768
#define C 128
#define EPS 1e-5f

typedef unsigned short u16;
using bfrag = __attribute__((ext_vector_type(8))) short;   // 8 bf16 = 4 VGPRs
using f32x4 = __attribute__((ext_vector_type(4))) float;

__device__ __forceinline__ float b2f(u16 u) {
  union { unsigned int i; float f; } x;
  x.i = ((unsigned int)u) << 16;
  return x.f;
}
__device__ __forceinline__ u16 f2b(float f) {
  union { float f; unsigned int i; } x;
  x.f = f;
  unsigned int r = x.i + 0x7FFFu + ((x.i >> 16) & 1u);   // RNE
  return (u16)(r >> 16);
}

// async global->LDS, 16 B per lane; LDS dest is wave-uniform base + lane*16.
__device__ __forceinline__ void g2l16(const void* g, void* l) {
  __builtin_amdgcn_global_load_lds(
      (const __attribute__((address_space(1))) unsigned int*)g,
      (__attribute__((address_space(3))) unsigned int*)l,
      16, 0, 0);
}

#define GG_W(N)                                                            \
  asm volatile("s_waitcnt vmcnt(" #N ")" ::: "memory");                    \
  __builtin_amdgcn_sched_barrier(0)

// counted vmcnt (own stage-group certified BEFORE barrier) + lgkm drain
// (prev stage's ds_reads, WAR safety) + block barrier + sched fence.
#define GG_WB(N)                                                           \
  asm volatile("s_waitcnt vmcnt(" #N ") lgkmcnt(0)" ::: "memory");         \
  __builtin_amdgcn_s_barrier();                                            \
  __builtin_amdgcn_sched_barrier(0)

// =====================================================================
// Gather-GEMM. Block = 128x128 output, 512 threads, 8 waves. Compute: 4
// tile-pairs -- pair p = (wv&3) owns rows [(p>>1)*64,+64) x cols
// [(p&1)*64,+64); wave computes kk2 = wv>>2 only; acc[4][4] f32x4 partial;
// 16 MFMA/stage/wave (setprio(1)-wrapped); 8 ds_read_b128/stage/wave.
// Partials reduced once at epilogue (waves 4-7 -> LDS -> waves 0-3 add).
// Stage s in [0, 2*NTAPS): tap = s<N?s:s-N, half = s<N?0:1 (channel-phase).
// LDS ring: buf[s&3] = A-half [128 rows][128B] + B-half [128 cols][128B].
// Stage group (issued at stage s-3, by wv -- barrier decouples): A 2 g2l16
// (rows wv*16+j*8+r8, chunk cs8^r8 of src+id*256+h*128), B 2 g2l16 (cols
// likewise of WT+tap*32K+h*128), idx 2 asm global_load_dword (for stage
// s+6, consumed s+3). Reads at slot (kk2*4+lsub)^(row&7): zero-conflict.
// EPI: 0 bf16 out; 1 bf16(acc*vmul); 2 f32 out.
// =====================================================================
template <int NTAPS, int EPI>
__global__ __launch_bounds__(512, 1)
void gg_kernel(const u16* __restrict__ src, const u16* __restrict__ WT,
               const int* __restrict__ nbr, u16* __restrict__ outb,
               float* __restrict__ outf, const u16* __restrict__ vmul) {
  __shared__ uint4 lds[8192];          // 128 KB: four 32 KB stage buffers
  char* const base = (char*)lds;
  char* const bufs[4] = {base, base + 32768, base + 65536, base + 98304};

  const int tid  = threadIdx.x;
  const int lane = tid & 63;
  const int wv   = tid >> 6;           // 0..7
  const int wq   = wv & 3;             // tile-pair id
  const int wr   = wq >> 1, wc = wq & 1;   // 2x2 grid of 64x64 tiles
  const int kk2w = wv >> 2;            // K-chunk owned by this wave (0/1)
  const int lsub = lane >> 4, lm = lane & 15;
  const int r8   = lane >> 3;          // DMA: row/col within instr (0..7)
  const int cs8  = lane & 7;           // DMA: chunk slot (0..7, 16 B)
  const int row0 = blockIdx.x * 128;

  f32x4 acc[4][4];
#pragma unroll
  for (int i = 0; i < 4; i++)
#pragma unroll
    for (int j = 0; j < 4; j++) acc[i][j] = (f32x4)(0.0f);

  // ---- idx loads (asm: invisible to waitcnt pass; retired by the manual
  // waits exactly 3 stages before use)
  auto loadIdx = [&](int (&d)[2], int st) {
    const int tp = st < NTAPS ? st : st - NTAPS;
#pragma unroll
    for (int j = 0; j < 2; j++) {
      const int gr = row0 + wv * 16 + j * 8 + r8;
      const int* p = nbr + (size_t)gr * NTAPS + tp;
      asm volatile("global_load_dword %0, %1, off"
                   : "=v"(d[j]) : "v"(p) : "memory");
    }
  };

  // ---- A half-stage for stage st (2 DMA/wave)
  auto stageA = [&](char* buf, const int (&id)[2], int st) {
    const int h = st < NTAPS ? 0 : 1;
#pragma unroll
    for (int j = 0; j < 2; j++) {
      const char* gp = (const char*)src + ((size_t)(unsigned)id[j] << 8)
                     + (h << 7) + ((cs8 ^ r8) << 4);
      g2l16(gp, buf + (wv * 16 + j * 8) * 128);
    }
  };

  // ---- B half-stage for stage st (2 DMA/wave)
  auto stageB = [&](char* buf, int st) {
    const int tp = st < NTAPS ? st : st - NTAPS;
    const int h = st < NTAPS ? 0 : 1;
    const char* wt = (const char*)WT + ((size_t)tp << 15) + (h << 7);
#pragma unroll
    for (int j = 0; j < 2; j++) {
      const int col = wv * 16 + j * 8 + r8;
      g2l16(wt + ((size_t)col << 8) + ((cs8 ^ r8) << 4),
            buf + 16384 + (wv * 16 + j * 8) * 128);
    }
  };

  // ---- one stage of MFMA (K-split): this wave does only kk2 = kk2w.
  // 64x64 tile: 4 af + 4 bg = 8 ds_read_b128, 16 MFMA. T5: the MFMA
  // cluster runs at wave priority 1 so MFMA-entering waves preempt
  // DMA-issuing waves on the CU scheduler (m201/m218b placement).
  auto computeS = [&](const char* buf) {
    bfrag af[4], bg[4];
#pragma unroll
    for (int rt = 0; rt < 4; rt++) {
      const int row = wr * 64 + rt * 16 + lm;
      af[rt] = *(const bfrag*)(buf + row * 128
                               + (((kk2w * 4 + lsub) ^ (row & 7)) << 4));
    }
#pragma unroll
    for (int ct = 0; ct < 4; ct++) {
      const int col = wc * 64 + ct * 16 + lm;
      bg[ct] = *(const bfrag*)(buf + 16384 + col * 128
                               + (((kk2w * 4 + lsub) ^ (col & 7)) << 4));
    }
    __builtin_amdgcn_s_setprio(1);
#pragma unroll
    for (int rt = 0; rt < 4; rt++)
#pragma unroll
      for (int ct = 0; ct < 4; ct++)
        acc[rt][ct] = __builtin_amdgcn_mfma_f32_16x16x32_bf16(
            af[rt], bg[ct], acc[rt][ct], 0, 0, 0);
    __builtin_amdgcn_s_setprio(0);
  };

  if constexpr (NTAPS == 1) {
    // dense 1x1: identity indices, both halves staged, one drain, K-split
    int idv[2];
#pragma unroll
    for (int j = 0; j < 2; j++) idv[j] = row0 + wv * 16 + j * 8 + r8;
    stageA(bufs[0], idv, 0); stageB(bufs[0], 0);   // tap0 h0
    stageA(bufs[1], idv, 1); stageB(bufs[1], 1);   // tap0 h1
    GG_WB(0);
    computeS(bufs[0]);
    computeS(bufs[1]);
  } else {
    constexpr int S = 2 * NTAPS;         // stages; N odd -> S-6 % 4 == 0
    int idr[4][2], ip0[2], ip1[2], ip2[2];
    // ---- prologue: idx(0..2) -> drain -> groups G(-3),G(-2),G(-1)
    loadIdx(ip0, 0); loadIdx(ip1, 1); loadIdx(ip2, 2);   // 6 ops
    GG_W(0);
    stageA(bufs[0], ip0, 0); stageB(bufs[0], 0); loadIdx(idr[1], 3);
    stageA(bufs[1], ip1, 1); stageB(bufs[1], 1); loadIdx(idr[2], 4);
    stageA(bufs[2], ip2, 2); stageB(bufs[2], 2); loadIdx(idr[3], 5);
    // FIFO = 18 = three 6-op groups; steady invariant holds from stage 0.

    // ---- main: stage s consumes idr[(s+1)&3] (idx of stage s+3, loaded at
    // s-3), loads idr[s&3] <- idx(stage s+6). One wait per stage.
#define GG_SUB(p)                                                          \
    GG_WB(12);                                                             \
    stageA(bufs[((p) + 3) & 3], idr[((p) + 1) & 3], s + (p) + 3);          \
    stageB(bufs[((p) + 3) & 3], s + (p) + 3);                              \
    loadIdx(idr[(p) & 3], s + (p) + 6);                                    \
    computeS(bufs[(p) & 3]);

#pragma unroll 1
    for (int s = 0; s < S - 6; s += 4) {
      GG_SUB(0)
      GG_SUB(1)
      GG_SUB(2)
      GG_SUB(3)
    }
#undef GG_SUB

    // ---- tail: stages S-6..S-1 (phases 0,1,2,3,0,1), no idx loads.
    // idx slots: S%4==2 -> idx(S-3)@slot1, idx(S-2)@slot2, idx(S-1)@slot3.
    GG_WB(12);
    stageA(bufs[3], idr[1], S - 3); stageB(bufs[3], S - 3);
    computeS(bufs[0]);                   // stage S-6
    GG_WB(10);
    stageA(bufs[0], idr[2], S - 2); stageB(bufs[0], S - 2);
    computeS(bufs[1]);                   // stage S-5
    GG_WB(8);
    stageA(bufs[1], idr[3], S - 1); stageB(bufs[1], S - 1);
    computeS(bufs[2]);                   // stage S-4
    GG_WB(8);
    computeS(bufs[3]);                   // stage S-3
    GG_WB(4);
    computeS(bufs[0]);                   // stage S-2
    GG_WB(0);
    computeS(bufs[1]);                   // stage S-1
  }

  // ---- K-split reduction: waves 4-7 park partials in LDS (64 KB, ring
  // buffers dead after last computeS); waves 0-3 add partner's partial.
  asm volatile("s_waitcnt lgkmcnt(0)" ::: "memory");
  __builtin_amdgcn_s_barrier();          // all compute ds_reads done
  __builtin_amdgcn_sched_barrier(0);
  if (wv >= 4) {
    char* dst = base + (size_t)(wv - 4) * 16384 + lane * 16;
#pragma unroll
    for (int rt = 0; rt < 4; rt++)
#pragma unroll
      for (int ct = 0; ct < 4; ct++)
        *(f32x4*)(dst + (rt * 4 + ct) * 1024) = acc[rt][ct];
  }
  asm volatile("s_waitcnt lgkmcnt(0)" ::: "memory");
  __builtin_amdgcn_s_barrier();
  __builtin_amdgcn_sched_barrier(0);

  // ---- epilogue write by waves 0-3. C/D: col = lane&15, row = lsub*4+reg.
  if (wv < 4) {
    const char* psrc = base + (size_t)wv * 16384 + lane * 16;
#pragma unroll
    for (int rt = 0; rt < 4; rt++) {
      const int rowb = row0 + wr * 64 + rt * 16 + lsub * 4;
#pragma unroll
      for (int ct = 0; ct < 4; ct++) {
        const f32x4 part = *(const f32x4*)(psrc + (rt * 4 + ct) * 1024);
        const f32x4 v4 = acc[rt][ct] + part;
        const int c = wc * 64 + ct * 16 + lm;
#pragma unroll
        for (int reg = 0; reg < 4; reg++) {
          const size_t off = (size_t)(rowb + reg) * C + c;
          const float v = v4[reg];
          if (EPI == 0)      outb[off] = f2b(v);
          else if (EPI == 1) outb[off] = f2b(v * b2f(vmul[off]));
          else               outf[off] = v;
        }
      }
    }
  }
}

// ---- f32 -> bf16 bulk convert (for x) ------------------------------------
__global__ __launch_bounds__(256)
void cvt_kernel(const float* __restrict__ x, u16* __restrict__ xb) {
  const int i = (blockIdx.x * 256 + threadIdx.x) * 4;
  const float4 v = *(const float4*)(x + i);
  ushort4 o;
  o.x = f2b(v.x); o.y = f2b(v.y); o.z = f2b(v.z); o.w = f2b(v.w);
  *(ushort4*)(xb + i) = o;
}

// ---- weights: f32 [..,Cin,Cout] -> bf16 [..,Cout,Cin] --------------------
__global__ __launch_bounds__(256)
void wt_kernel(const float* __restrict__ W5, const float* __restrict__ W31,
               const float* __restrict__ W32, const float* __restrict__ Wa1,
               const float* __restrict__ Wv1,
               u16* __restrict__ T5, u16* __restrict__ T31, u16* __restrict__ T32,
               u16* __restrict__ Ta1, u16* __restrict__ Tv1) {
  const int b = blockIdx.x;
  const float* w;
  u16* o;
  if (b < 125)       { w = W5  + (size_t)b * 16384;         o = T5  + (size_t)b * 16384; }
  else if (b < 152)  { w = W31 + (size_t)(b - 125) * 16384; o = T31 + (size_t)(b - 125) * 16384; }
  else if (b < 179)  { w = W32 + (size_t)(b - 152) * 16384; o = T32 + (size_t)(b - 152) * 16384; }
  else if (b == 179) { w = Wa1; o = Ta1; }
  else               { w = Wv1; o = Tv1; }
  __shared__ u16 tile[128 * 129];
  for (int i = threadIdx.x; i < C * C; i += 256)
    tile[(i & 127) * 129 + (i >> 7)] = f2b(w[i]);
  __syncthreads();
  for (int i = threadIdx.x; i < C * C; i += 256)
    o[i] = tile[(i >> 7) * 129 + (i & 127)];
}

// ---- BN partials (f32): block b owns rows [b*128, +128) ------------------
__global__ __launch_bounds__(256)
void bnp_kernel(const float* __restrict__ t, float* __restrict__ psum,
                float* __restrict__ psq) {
  const int b = blockIdx.x;
  const int c = threadIdx.x & 127;
  const int h = threadIdx.x >> 7;
  const float* p = t + (size_t)(b * 128 + h * 64) * C + c;
  float s = 0.f, q = 0.f;
#pragma unroll 8
  for (int j = 0; j < 64; j++) {
    const float v = p[(size_t)j * C];
    s += v; q += v * v;
  }
  __shared__ float ls[256], lq[256];
  ls[threadIdx.x] = s; lq[threadIdx.x] = q;
  __syncthreads();
  if (h == 0) {
    psum[b * 128 + c] = ls[c] + ls[c + 128];
    psq[b * 128 + c]  = lq[c] + lq[c + 128];
  }
}

// ---- bnfin: block c reduces 256 partials (parallel) ----------------------
__global__ __launch_bounds__(256)
void bnfin_kernel(const float* __restrict__ psum, const float* __restrict__ psq,
                  const float* __restrict__ gamma, const float* __restrict__ beta,
                  float* __restrict__ scale, float* __restrict__ shift) {
  const int c = blockIdx.x;
  const int t = threadIdx.x;
  float s = psum[(size_t)t * 128 + c];
  float q = psq[(size_t)t * 128 + c];
#pragma unroll
  for (int o = 32; o > 0; o >>= 1) {
    s += __shfl_down(s, o);
    q += __shfl_down(q, o);
  }
  __shared__ float ls[4], lq[4];
  if ((t & 63) == 0) { ls[t >> 6] = s; lq[t >> 6] = q; }
  __syncthreads();
  if (t == 0) {
    s = ls[0] + ls[1] + ls[2] + ls[3];
    q = lq[0] + lq[1] + lq[2] + lq[3];
    const float mean = s * (1.0f / NPTS);
    const float var  = q * (1.0f / NPTS) - mean * mean;
    const float sc   = rsqrtf(var + EPS) * gamma[c];
    scale[c] = sc;
    shift[c] = beta[c] - mean * sc;
  }
}

// ---- ew1: o = t*sc+sh + x; res=bf16(o); h=bf16(relu o) -------------------
__global__ __launch_bounds__(256)
void ew1_kernel(const float* __restrict__ t, const float* __restrict__ x,
                const float* __restrict__ scale, const float* __restrict__ shift,
                u16* __restrict__ res, u16* __restrict__ h) {
  const int i = blockIdx.x * 256 + threadIdx.x;
  const int c = i & 127;
  const float o = t[i] * scale[c] + shift[c] + x[i];
  res[i] = f2b(o);
  h[i] = f2b(o < 0.f ? 0.f : o);
}

// ---- ew2: y = relu(t2*sc+sh + res) -> f32 d_out --------------------------
__global__ __launch_bounds__(256)
void ew2_kernel(const float* __restrict__ t2, const u16* __restrict__ res,
                const float* __restrict__ scale, const float* __restrict__ shift,
                float* __restrict__ y) {
  const int i = blockIdx.x * 256 + threadIdx.x;
  const int c = i & 127;
  const float o = t2[i] * scale[c] + shift[c] + b2f(res[i]);
  y[i] = o < 0.f ? 0.f : o;
}

// =====================================================================
extern "C" void kernel_launch(void* const* d_in, const int* in_sizes, int n_in,
                              void* d_out, int out_size, void* d_ws, size_t ws_size,
                              hipStream_t stream) {
  (void)in_sizes; (void)n_in; (void)out_size; (void)ws_size;

  const float* x   = (const float*)d_in[0];
  const float* Wa1 = (const float*)d_in[1];
  const float* Wv1 = (const float*)d_in[2];
  const float* W5  = (const float*)d_in[3];
  const float* W31 = (const float*)d_in[4];
  const float* W32 = (const float*)d_in[5];
  const float* g1  = (const float*)d_in[6];
  const float* b1  = (const float*)d_in[7];
  const float* g2  = (const float*)d_in[8];
  const float* b2  = (const float*)d_in[9];
  const int* nbr5  = (const int*)d_in[10];
  const int* nbr3a = (const int*)d_in[11];
  const int* nbr3b = (const int*)d_in[12];

  // ---- workspace (~39.8 MB) ----
  char* w = (char*)d_ws;
  u16* WT5  = (u16*)w; w += 4096000;
  u16* WT31 = (u16*)w; w += 884736;
  u16* WT32 = (u16*)w; w += 884736;
  u16* WTa1 = (u16*)w; w += 32768;
  u16* WTv1 = (u16*)w; w += 32768;
  char* AV  = w;       w += 16777216;          // a | v ; later t/t2 (f32)
  u16*   a_b = (u16*)AV;
  u16*   v_b = (u16*)(AV + 8388608);
  float* tf  = (float*)AV;
  u16* g_b  = (u16*)w; w += 8388608;           // g ; later res (bf16)
  u16* h_b  = (u16*)w; w += 8388608;           // xb first, then h (bf16)
  u16* xb   = h_b;                             // alias: xb dead before ew1
  float* psum = (float*)w; w += 131072;
  float* psq  = (float*)w; w += 131072;
  float* sc1  = (float*)w; w += 512;
  float* sh1  = (float*)w; w += 512;
  float* sc2  = (float*)w; w += 512;
  float* sh2  = (float*)w; w += 512;

  const dim3 B512(512), GG(NPTS / 128), B256(256), GBN(256), GEW(NPTS * C / 256);
  float* yout = (float*)d_out;

  cvt_kernel<<<dim3(NPTS * C / 1024), B256, 0, stream>>>(x, xb);
  wt_kernel<<<dim3(181), B256, 0, stream>>>(W5, W31, W32, Wa1, Wv1,
                                            WT5, WT31, WT32, WTa1, WTv1);

  // a = xb @ Wa1 ; v = xb @ Wv1
  gg_kernel<1, 0><<<GG, B512, 0, stream>>>(xb, WTa1, nullptr, a_b, nullptr, nullptr);
  gg_kernel<1, 0><<<GG, B512, 0, stream>>>(xb, WTv1, nullptr, v_b, nullptr, nullptr);

  // g = gather125(a)@W5 * v
  gg_kernel<125, 1><<<GG, B512, 0, stream>>>(a_b, WT5, nbr5, g_b, nullptr, v_b);

  // t = gather27(g)@W31 -> f32 over AV (a,v dead)
  gg_kernel<27, 2><<<GG, B512, 0, stream>>>(g_b, WT31, nbr3a, nullptr, tf, nullptr);
  bnp_kernel<<<GBN, B256, 0, stream>>>(tf, psum, psq);
  bnfin_kernel<<<dim3(128), B256, 0, stream>>>(psum, psq, g1, b1, sc1, sh1);
  ew1_kernel<<<GEW, B256, 0, stream>>>(tf, x, sc1, sh1, g_b, h_b);   // res->g_b, h->h_b (xb dead)

  // t2 = gather27(h)@W32 -> f32 over AV (t dead)
  gg_kernel<27, 2><<<GG, B512, 0, stream>>>(h_b, WT32, nbr3b, nullptr, tf, nullptr);
  bnp_kernel<<<GBN, B256, 0, stream>>>(tf, psum, psq);
  bnfin_kernel<<<dim3(128), B256, 0, stream>>>(psum, psq, g2, b2, sc2, sh2);
  ew2_kernel<<<GEW, B256, 0, stream>>>(tf, g_b, sc2, sh2, yout);
}